// Round 1
// 1077.753 us; speedup vs baseline: 1.0201x; 1.0201x over previous
//
#include <hip/hip_runtime.h>
#include <stdint.h>

typedef unsigned short u16;
typedef __bf16 bf16x8 __attribute__((ext_vector_type(8)));
typedef float f32x4 __attribute__((ext_vector_type(4)));

#define NNODES 150000
#define KNBR 27
#define LDX 128
#define MR1 64     // rows per block conv1 (4 waves x 16 rows)
#define MR2 32     // rows per block conv2 (2 row-halves x 16; g/h wave split)
#define APAD 72    // epilogue LDS row stride (u16)

static __device__ __forceinline__ u16 f2bf(float f){
  union { float f; uint32_t i; } v; v.f = f;
  uint32_t x = v.i;
  uint32_t r = (x + 0x7fffu + ((x >> 16) & 1u)) >> 16;  // RNE
  return (u16)r;
}
static __device__ __forceinline__ float lrelu(float v){ return v >= 0.f ? v : 0.2f*v; }

// fp32 weight (krows x 64) -> bf16 MFMA B-fragment order
__global__ void reformat_w(const float* __restrict__ src, u16* __restrict__ dst, int ksteps){
  int idx = blockIdx.x*256 + threadIdx.x;
  int total = ksteps*4*64;
  if (idx >= total) return;
  int lane = idx & 63;
  int ctile = (idx >> 6) & 3;
  int t = idx >> 8;
  int quad = lane >> 4, m = lane & 15;
  union { u16 h[8]; float4 v; } tmp;
  const float* s = src + ((size_t)(t*32 + quad*8))*64 + ctile*16 + m;
  #pragma unroll
  for (int j=0;j<8;j++) tmp.h[j] = f2bf(s[j*64]);
  *reinterpret_cast<float4*>(dst + (size_t)idx*8) = tmp.v;
}

// x cols 64..127 (fp32, LDX stride) -> bf16 table sb (N x 64)
__global__ void conv_x2(const float* __restrict__ x, u16* __restrict__ sb){
  int idx = blockIdx.x*256 + threadIdx.x;
  int e = idx*8;
  if (e >= NNODES*64) return;
  int row = e >> 6, col = e & 63;
  const float* s = x + (size_t)row*LDX + 64 + col;
  float4 a = *reinterpret_cast<const float4*>(s);
  float4 b = *reinterpret_cast<const float4*>(s+4);
  union { u16 h[8]; float4 v; } t;
  t.h[0]=f2bf(a.x); t.h[1]=f2bf(a.y); t.h[2]=f2bf(a.z); t.h[3]=f2bf(a.w);
  t.h[4]=f2bf(b.x); t.h[5]=f2bf(b.y); t.h[6]=f2bf(b.z); t.h[7]=f2bf(b.w);
  *reinterpret_cast<float4*>(sb + e) = t.v;
}

// u[:,0:64] = lrelu(lrelu(gather(sb) @ w1g) @ w2g); u[:,64:128] = h-version.
// 16 rows/wave (1 M-tile), g+h share the gathered A fragments.
__global__ __launch_bounds__(256,3) void conv1_fused(
    const u16* __restrict__ sb,
    const int* __restrict__ nbr,
    const u16* __restrict__ wb1g, const u16* __restrict__ wb1h,
    const u16* __restrict__ wb2g, const u16* __restrict__ wb2h,
    u16* __restrict__ u)
{
  extern __shared__ char smem[];
  int* s_idx = (int*)smem;                 // [MR1*KNBR] = 6912 B
  u16* s_a   = (u16*)smem;                 // [2][MR1*APAD] = 18432 B (after k-loop)

  int tid = threadIdx.x;
  int row0 = blockIdx.x * MR1;
  for (int i = tid; i < MR1*KNBR; i += 256){
    int r = i / KNBR, kk = i - r*KNBR;
    int row = row0 + r;
    s_idx[i] = (row < NNODES) ? nbr[row*KNBR + kk] : 0;
  }
  __syncthreads();

  int lane = tid & 63;
  int wv = tid >> 6;
  int quad = lane >> 4, m = lane & 15;
  int qoff = quad * 8;
  int wrow = wv * 16;                       // this wave's first row (1 M-tile)
  const int* idx0 = &s_idx[(wrow + m)*KNBR];

  f32x4 accg[4], acch[4];
  f32x4 zz = {0.f,0.f,0.f,0.f};
  #pragma unroll
  for (int i=0;i<4;i++){ accg[i]=zz; acch[i]=zz; }

  bf16x8 ac[2], an[2], b0[8], b1[8];
  {
    // prologue order: A(0), B(0), B(1), A(1)  -> b-waits never drain A(1)
    const u16* r0 = sb + (size_t)idx0[0]*64 + qoff;
    ac[0] = *reinterpret_cast<const bf16x8*>(r0);
    ac[1] = *reinterpret_cast<const bf16x8*>(r0 + 32);
    #pragma unroll
    for (int ct=0;ct<4;ct++){
      b0[ct]   = *reinterpret_cast<const bf16x8*>(wb1g + (((size_t)0*4+ct)*64 + lane)*8);
      b0[4+ct] = *reinterpret_cast<const bf16x8*>(wb1h + (((size_t)0*4+ct)*64 + lane)*8);
      b1[ct]   = *reinterpret_cast<const bf16x8*>(wb1g + (((size_t)1*4+ct)*64 + lane)*8);
      b1[4+ct] = *reinterpret_cast<const bf16x8*>(wb1h + (((size_t)1*4+ct)*64 + lane)*8);
    }
    const u16* r1 = sb + (size_t)idx0[1]*64 + qoff;
    an[0] = *reinterpret_cast<const bf16x8*>(r1);
    an[1] = *reinterpret_cast<const bf16x8*>(r1 + 32);
  }

  #pragma unroll
  for (int k=0;k<KNBR;k++){
    // t0 = 2k
    #pragma unroll
    for (int ct=0;ct<4;ct++){
      accg[ct] = __builtin_amdgcn_mfma_f32_16x16x32_bf16(ac[0], b0[ct],   accg[ct], 0,0,0);
      acch[ct] = __builtin_amdgcn_mfma_f32_16x16x32_bf16(ac[0], b0[4+ct], acch[ct], 0,0,0);
    }
    if (k+1 < KNBR){
      int t2 = 2*k + 2;
      #pragma unroll
      for (int ct=0;ct<4;ct++){
        b0[ct]   = *reinterpret_cast<const bf16x8*>(wb1g + (((size_t)t2*4+ct)*64 + lane)*8);
        b0[4+ct] = *reinterpret_cast<const bf16x8*>(wb1h + (((size_t)t2*4+ct)*64 + lane)*8);
      }
    }
    // t1 = 2k+1
    #pragma unroll
    for (int ct=0;ct<4;ct++){
      accg[ct] = __builtin_amdgcn_mfma_f32_16x16x32_bf16(ac[1], b1[ct],   accg[ct], 0,0,0);
      acch[ct] = __builtin_amdgcn_mfma_f32_16x16x32_bf16(ac[1], b1[4+ct], acch[ct], 0,0,0);
    }
    if (k+1 < KNBR){
      int t3 = 2*k + 3;
      #pragma unroll
      for (int ct=0;ct<4;ct++){
        b1[ct]   = *reinterpret_cast<const bf16x8*>(wb1g + (((size_t)t3*4+ct)*64 + lane)*8);
        b1[4+ct] = *reinterpret_cast<const bf16x8*>(wb1h + (((size_t)t3*4+ct)*64 + lane)*8);
      }
    }
    // fence: keep all B-issues of this iter before the A-issue below
    __builtin_amdgcn_sched_barrier(0);
    bf16x8 at0 = ac[0], at1 = ac[1];
    if (k+2 < KNBR){
      const u16* rr = sb + (size_t)idx0[k+2]*64 + qoff;
      at0 = *reinterpret_cast<const bf16x8*>(rr);
      at1 = *reinterpret_cast<const bf16x8*>(rr + 32);
    }
    ac[0]=an[0]; ac[1]=an[1]; an[0]=at0; an[1]=at1;
  }
  __syncthreads();   // s_idx dead; reuse LDS for epilogue tiles

  // lrelu -> bf16 tiles in LDS (C-layout -> A-layout round trip)
  u16* sa0 = s_a;
  u16* sa1 = s_a + MR1*APAD;
  #pragma unroll
  for (int ct=0;ct<4;ct++){
    #pragma unroll
    for (int i=0;i<4;i++){
      int rl = wrow + quad*4 + i;
      int col = ct*16 + m;
      sa0[rl*APAD + col] = f2bf(lrelu(accg[ct][i]));
      sa1[rl*APAD + col] = f2bf(lrelu(acch[ct][i]));
    }
  }
  __syncthreads();

  f32x4 dg[4], dh[4];
  #pragma unroll
  for (int i=0;i<4;i++){ dg[i]=zz; dh[i]=zz; }
  #pragma unroll
  for (int c=0;c<2;c++){
    bf16x8 ag = *reinterpret_cast<const bf16x8*>(&sa0[(wrow + m)*APAD + c*32 + qoff]);
    bf16x8 ah = *reinterpret_cast<const bf16x8*>(&sa1[(wrow + m)*APAD + c*32 + qoff]);
    #pragma unroll
    for (int ct=0;ct<4;ct++){
      bf16x8 bg = *reinterpret_cast<const bf16x8*>(wb2g + (((size_t)c*4+ct)*64 + lane)*8);
      dg[ct] = __builtin_amdgcn_mfma_f32_16x16x32_bf16(ag, bg, dg[ct], 0,0,0);
      bf16x8 bh = *reinterpret_cast<const bf16x8*>(wb2h + (((size_t)c*4+ct)*64 + lane)*8);
      dh[ct] = __builtin_amdgcn_mfma_f32_16x16x32_bf16(ah, bh, dh[ct], 0,0,0);
    }
  }
  #pragma unroll
  for (int ct=0;ct<4;ct++){
    #pragma unroll
    for (int i=0;i<4;i++){
      int row = row0 + wrow + quad*4 + i;
      if (row < NNODES){
        int col = ct*16 + m;
        u[(size_t)row*128 + col]      = f2bf(lrelu(dg[ct][i]));
        u[(size_t)row*128 + 64 + col] = f2bf(lrelu(dh[ct][i]));
      }
    }
  }
}

// bg = gather(u[:,:64]) @ w3g ; bh = gather(u[:,64:]) @ w3h ;
// y = x_prev * exp(2*sigmoid(bg)-1) + bh -> out fp32; optionally y -> yb bf16.
// g/h split across wave pairs: waves {0,1}=g rows[0..15],[16..31]; {2,3}=h same rows.
// 16 rows/wave -> ~90 VGPRs -> 4-5 blocks/CU for latency hiding.
__global__ __launch_bounds__(256,4) void conv2_coupling(
    const u16* __restrict__ ub,
    const int* __restrict__ nbr,
    const u16* __restrict__ wbg, const u16* __restrict__ wbh,
    const float* __restrict__ x, int xcol0,
    float* __restrict__ out, int ycol0,
    u16* __restrict__ yb, int write_yb)
{
  extern __shared__ char smem[];
  int*   s_idx = (int*)smem;     // [MR2*KNBR] = 3456 B (k-loop)
  float* s_bh  = (float*)smem;   // [MR2*65]   = 8320 B (epilogue)

  int tid = threadIdx.x;
  int row0 = blockIdx.x * MR2;
  for (int i = tid; i < MR2*KNBR; i += 256){
    int r = i / KNBR, kk = i - r*KNBR;
    int row = row0 + r;
    s_idx[i] = (row < NNODES) ? nbr[row*KNBR + kk] : 0;
  }
  __syncthreads();

  int lane = tid & 63;
  int wv = tid >> 6;
  int gh = wv >> 1;                 // 0 = g matrix, 1 = h matrix
  int rhalf = wv & 1;               // which 16-row half
  int quad = lane >> 4, m = lane & 15;
  int qoff = quad * 8;
  int wrow = rhalf * 16;
  const int* idx0 = &s_idx[(wrow + m)*KNBR];
  const u16* wb = gh ? wbh : wbg;
  const size_t ghoff = (size_t)gh * 64;   // h reads ub cols 64..127

  f32x4 acc[4];
  f32x4 zz = {0.f,0.f,0.f,0.f};
  #pragma unroll
  for (int i=0;i<4;i++) acc[i] = zz;

  bf16x8 ac[2], an[2], b0[4], b1[4];
  {
    // prologue order: A(0), B(0), B(1), A(1)
    const u16* r0 = ub + (size_t)idx0[0]*128 + ghoff + qoff;
    ac[0] = *reinterpret_cast<const bf16x8*>(r0);
    ac[1] = *reinterpret_cast<const bf16x8*>(r0 + 32);
    #pragma unroll
    for (int ct=0;ct<4;ct++){
      b0[ct] = *reinterpret_cast<const bf16x8*>(wb + (((size_t)0*4+ct)*64 + lane)*8);
      b1[ct] = *reinterpret_cast<const bf16x8*>(wb + (((size_t)1*4+ct)*64 + lane)*8);
    }
    const u16* r1 = ub + (size_t)idx0[1]*128 + ghoff + qoff;
    an[0] = *reinterpret_cast<const bf16x8*>(r1);
    an[1] = *reinterpret_cast<const bf16x8*>(r1 + 32);
  }

  #pragma unroll
  for (int k=0;k<KNBR;k++){
    // t0 = 2k (input channels 0..31 of neighbor k)
    #pragma unroll
    for (int ct=0;ct<4;ct++)
      acc[ct] = __builtin_amdgcn_mfma_f32_16x16x32_bf16(ac[0], b0[ct], acc[ct], 0,0,0);
    if (k+1 < KNBR){
      int t2 = 2*k + 2;
      #pragma unroll
      for (int ct=0;ct<4;ct++)
        b0[ct] = *reinterpret_cast<const bf16x8*>(wb + (((size_t)t2*4+ct)*64 + lane)*8);
    }
    // t1 = 2k+1 (channels 32..63)
    #pragma unroll
    for (int ct=0;ct<4;ct++)
      acc[ct] = __builtin_amdgcn_mfma_f32_16x16x32_bf16(ac[1], b1[ct], acc[ct], 0,0,0);
    if (k+1 < KNBR){
      int t3 = 2*k + 3;
      #pragma unroll
      for (int ct=0;ct<4;ct++)
        b1[ct] = *reinterpret_cast<const bf16x8*>(wb + (((size_t)t3*4+ct)*64 + lane)*8);
    }
    // fence: keep all B-issues of this iter before the A-issue below
    __builtin_amdgcn_sched_barrier(0);
    bf16x8 at0 = ac[0], at1 = ac[1];
    if (k+2 < KNBR){
      const u16* rr = ub + (size_t)idx0[k+2]*128 + ghoff + qoff;
      at0 = *reinterpret_cast<const bf16x8*>(rr);
      at1 = *reinterpret_cast<const bf16x8*>(rr + 32);
    }
    ac[0]=an[0]; ac[1]=an[1]; an[0]=at0; an[1]=at1;
  }

  // ---- coupling epilogue: h-waves publish bh via LDS; g-waves combine ----
  float xv[4][4];
  if (gh == 0){
    #pragma unroll
    for (int ct=0;ct<4;ct++){
      #pragma unroll
      for (int i=0;i<4;i++){
        int row = row0 + wrow + quad*4 + i;
        xv[ct][i] = (row < NNODES) ? x[(size_t)row*LDX + xcol0 + ct*16 + m] : 0.f;
      }
    }
  }
  __syncthreads();   // all s_idx reads done; safe to overwrite smem
  if (gh == 1){
    #pragma unroll
    for (int ct=0;ct<4;ct++){
      #pragma unroll
      for (int i=0;i<4;i++){
        int rl = wrow + quad*4 + i;
        s_bh[rl*65 + ct*16 + m] = acc[ct][i];
      }
    }
  }
  __syncthreads();
  if (gh == 0){
    #pragma unroll
    for (int ct=0;ct<4;ct++){
      #pragma unroll
      for (int i=0;i<4;i++){
        int rl = wrow + quad*4 + i;
        int row = row0 + rl;
        if (row < NNODES){
          int col = ct*16 + m;
          float bg = acc[ct][i];
          float bh = s_bh[rl*65 + col];
          float s = 1.f/(1.f + __expf(-bg));
          s = __expf(2.f*s - 1.f);
          float y = xv[ct][i]*s + bh;
          out[(size_t)row*LDX + ycol0 + col] = y;
          if (write_yb) yb[(size_t)row*64 + col] = f2bf(y);
        }
      }
    }
  }
}

extern "C" void kernel_launch(void* const* d_in, const int* in_sizes, int n_in,
                              void* d_out, int out_size, void* d_ws, size_t ws_size,
                              hipStream_t stream)
{
  const float* x   = (const float*)d_in[0];
  const int*   nbr = (const int*)d_in[1];
  const float* g1_w1=(const float*)d_in[2],  *g1_w2=(const float*)d_in[3],  *g1_w3=(const float*)d_in[4];
  const float* g2_w1=(const float*)d_in[5],  *g2_w2=(const float*)d_in[6],  *g2_w3=(const float*)d_in[7];
  const float* h1_w1=(const float*)d_in[8],  *h1_w2=(const float*)d_in[9],  *h1_w3=(const float*)d_in[10];
  const float* h2_w1=(const float*)d_in[11], *h2_w2=(const float*)d_in[12], *h2_w3=(const float*)d_in[13];
  float* out = (float*)d_out;
  u16* ws = (u16*)d_ws;

  const size_t WBB = (size_t)54*4*64*8;  // 1728-row weights (bf16 frags)
  const size_t WBS = (size_t)2*4*64*8;   // 64-row weights
  u16* p = ws;
  u16* wb_g2_1=p; p+=WBB;  u16* wb_h2_1=p; p+=WBB;
  u16* wb_g2_2=p; p+=WBS;  u16* wb_h2_2=p; p+=WBS;
  u16* wb_g2_3=p; p+=WBB;  u16* wb_h2_3=p; p+=WBB;
  u16* wb_g1_1=p; p+=WBB;  u16* wb_h1_1=p; p+=WBB;
  u16* wb_g1_2=p; p+=WBS;  u16* wb_h1_2=p; p+=WBS;
  u16* wb_g1_3=p; p+=WBB;  u16* wb_h1_3=p; p+=WBB;
  u16* ub = p; p += (size_t)NNODES*128;   // interleaved [g|h] bf16
  u16* sb = p; p += (size_t)NNODES*64;    // gather source (x2 bf16, then y1 bf16)

  reformat_w<<<54,256,0,stream>>>(g2_w1, wb_g2_1, 54);
  reformat_w<<<54,256,0,stream>>>(h2_w1, wb_h2_1, 54);
  reformat_w<<<2,256,0,stream>>>(g2_w2, wb_g2_2, 2);
  reformat_w<<<2,256,0,stream>>>(h2_w2, wb_h2_2, 2);
  reformat_w<<<54,256,0,stream>>>(g2_w3, wb_g2_3, 54);
  reformat_w<<<54,256,0,stream>>>(h2_w3, wb_h2_3, 54);
  reformat_w<<<54,256,0,stream>>>(g1_w1, wb_g1_1, 54);
  reformat_w<<<54,256,0,stream>>>(h1_w1, wb_h1_1, 54);
  reformat_w<<<2,256,0,stream>>>(g1_w2, wb_g1_2, 2);
  reformat_w<<<2,256,0,stream>>>(h1_w2, wb_h1_2, 2);
  reformat_w<<<54,256,0,stream>>>(g1_w3, wb_g1_3, 54);
  reformat_w<<<54,256,0,stream>>>(h1_w3, wb_h1_3, 54);

  conv_x2<<<(NNODES*64/8 + 255)/256, 256, 0, stream>>>(x, sb);

  int nblk1 = (NNODES + MR1 - 1)/MR1;     // 2344
  int nblk2 = (NNODES + MR2 - 1)/MR2;     // 4688
  size_t c1_lds = (size_t)2*MR1*APAD*2;   // 18432 B (>= s_idx 6912 B)
  size_t c2_lds = (size_t)MR2*65*4;       // 8320 B  (>= s_idx 3456 B)

  // Phase A: sb = x2(bf16); y1 -> out cols 0..63 + sb(bf16)
  conv1_fused<<<nblk1,256,c1_lds,stream>>>(sb, nbr, wb_g2_1, wb_h2_1, wb_g2_2, wb_h2_2, ub);
  conv2_coupling<<<nblk2,256,c2_lds,stream>>>(ub, nbr, wb_g2_3, wb_h2_3, x, 0, out, 0, sb, 1);
  // Phase B: sb = y1(bf16); y2 -> out cols 64..127
  conv1_fused<<<nblk1,256,c1_lds,stream>>>(sb, nbr, wb_g1_1, wb_h1_1, wb_g1_2, wb_h1_2, ub);
  conv2_coupling<<<nblk2,256,c2_lds,stream>>>(ub, nbr, wb_g1_3, wb_h1_3, x, 64, out, 64, sb, 0);
}

// Round 2
// 967.956 us; speedup vs baseline: 1.1358x; 1.1134x over previous
//
#include <hip/hip_runtime.h>
#include <stdint.h>

typedef unsigned short u16;
typedef __bf16 bf16x8 __attribute__((ext_vector_type(8)));
typedef float f32x4 __attribute__((ext_vector_type(4)));

#define NNODES 150000
#define KNBR 27
#define LDX 128
#define MR 64      // rows per block (both kernels): 2 row-halves x 32 rows; g/h wave split
#define APAD 72    // epilogue LDS row stride (u16)

static __device__ __forceinline__ u16 f2bf(float f){
  union { float f; uint32_t i; } v; v.f = f;
  uint32_t x = v.i;
  uint32_t r = (x + 0x7fffu + ((x >> 16) & 1u)) >> 16;  // RNE
  return (u16)r;
}
static __device__ __forceinline__ float lrelu(float v){ return v >= 0.f ? v : 0.2f*v; }

// fp32 weight (krows x 64) -> bf16 MFMA B-fragment order
__global__ void reformat_w(const float* __restrict__ src, u16* __restrict__ dst, int ksteps){
  int idx = blockIdx.x*256 + threadIdx.x;
  int total = ksteps*4*64;
  if (idx >= total) return;
  int lane = idx & 63;
  int ctile = (idx >> 6) & 3;
  int t = idx >> 8;
  int quad = lane >> 4, m = lane & 15;
  union { u16 h[8]; float4 v; } tmp;
  const float* s = src + ((size_t)(t*32 + quad*8))*64 + ctile*16 + m;
  #pragma unroll
  for (int j=0;j<8;j++) tmp.h[j] = f2bf(s[j*64]);
  *reinterpret_cast<float4*>(dst + (size_t)idx*8) = tmp.v;
}

// x cols 64..127 (fp32, LDX stride) -> bf16 table sb (N x 64)
__global__ void conv_x2(const float* __restrict__ x, u16* __restrict__ sb){
  int idx = blockIdx.x*256 + threadIdx.x;
  int e = idx*8;
  if (e >= NNODES*64) return;
  int row = e >> 6, col = e & 63;
  const float* s = x + (size_t)row*LDX + 64 + col;
  float4 a = *reinterpret_cast<const float4*>(s);
  float4 b = *reinterpret_cast<const float4*>(s+4);
  union { u16 h[8]; float4 v; } t;
  t.h[0]=f2bf(a.x); t.h[1]=f2bf(a.y); t.h[2]=f2bf(a.z); t.h[3]=f2bf(a.w);
  t.h[4]=f2bf(b.x); t.h[5]=f2bf(b.y); t.h[6]=f2bf(b.z); t.h[7]=f2bf(b.w);
  *reinterpret_cast<float4*>(sb + e) = t.v;
}

// u[:,0:64] = lrelu(lrelu(gather(sb) @ w1g) @ w2g); u[:,64:128] = h-version.
// 4 waves: wave = (gh, rhalf); 32 rows/wave (2 M-tiles), one matrix per wave.
__global__ __launch_bounds__(256,4) void conv1_fused(
    const u16* __restrict__ sb,
    const int* __restrict__ nbr,
    const u16* __restrict__ wb1g, const u16* __restrict__ wb1h,
    const u16* __restrict__ wb2g, const u16* __restrict__ wb2h,
    u16* __restrict__ u)
{
  extern __shared__ char smem[];
  int* s_idx = (int*)smem;                 // [MR*KNBR] = 6912 B
  u16* s_a   = (u16*)smem;                 // [4][32*APAD] = 18432 B (after k-loop)

  int tid = threadIdx.x;
  int row0 = blockIdx.x * MR;
  for (int i = tid; i < MR*KNBR; i += 256){
    int r = i / KNBR, kk = i - r*KNBR;
    int row = row0 + r;
    s_idx[i] = (row < NNODES) ? nbr[row*KNBR + kk] : 0;
  }
  __syncthreads();

  int lane = tid & 63;
  int wv = tid >> 6;
  int gh = wv >> 1;                 // 0 = g matrix, 1 = h matrix
  int rhalf = wv & 1;               // which 32-row half
  int quad = lane >> 4, m = lane & 15;
  int qoff = quad * 8;
  int wrow = rhalf * 32;
  const int* idx0 = &s_idx[(wrow + m)*KNBR];       // M-tile 0
  const int* idx1 = &s_idx[(wrow + 16 + m)*KNBR];  // M-tile 1
  const u16* w1 = gh ? wb1h : wb1g;
  const u16* w2 = gh ? wb2h : wb2g;

  f32x4 acc[2][4];
  f32x4 zz = {0.f,0.f,0.f,0.f};
  #pragma unroll
  for (int mt=0;mt<2;mt++)
    #pragma unroll
    for (int i=0;i<4;i++) acc[mt][i] = zz;

  bf16x8 ac[4], an[4], b0[4], b1[4];
  {
    // prologue order: A(0), B(0), B(1), A(1) -> B-waits never drain A(1)
    const u16* r0 = sb + (size_t)idx0[0]*64 + qoff;
    const u16* r1 = sb + (size_t)idx1[0]*64 + qoff;
    ac[0] = *reinterpret_cast<const bf16x8*>(r0);
    ac[1] = *reinterpret_cast<const bf16x8*>(r0 + 32);
    ac[2] = *reinterpret_cast<const bf16x8*>(r1);
    ac[3] = *reinterpret_cast<const bf16x8*>(r1 + 32);
    #pragma unroll
    for (int ct=0;ct<4;ct++){
      b0[ct] = *reinterpret_cast<const bf16x8*>(w1 + (((size_t)0*4+ct)*64 + lane)*8);
      b1[ct] = *reinterpret_cast<const bf16x8*>(w1 + (((size_t)1*4+ct)*64 + lane)*8);
    }
    const u16* s0 = sb + (size_t)idx0[1]*64 + qoff;
    const u16* s1 = sb + (size_t)idx1[1]*64 + qoff;
    an[0] = *reinterpret_cast<const bf16x8*>(s0);
    an[1] = *reinterpret_cast<const bf16x8*>(s0 + 32);
    an[2] = *reinterpret_cast<const bf16x8*>(s1);
    an[3] = *reinterpret_cast<const bf16x8*>(s1 + 32);
  }

  #pragma unroll
  for (int k=0;k<KNBR;k++){
    // t0 = 2k (channels 0..31)
    #pragma unroll
    for (int ct=0;ct<4;ct++){
      acc[0][ct] = __builtin_amdgcn_mfma_f32_16x16x32_bf16(ac[0], b0[ct], acc[0][ct], 0,0,0);
      acc[1][ct] = __builtin_amdgcn_mfma_f32_16x16x32_bf16(ac[2], b0[ct], acc[1][ct], 0,0,0);
    }
    if (k+1 < KNBR){
      int t2 = 2*k + 2;
      #pragma unroll
      for (int ct=0;ct<4;ct++)
        b0[ct] = *reinterpret_cast<const bf16x8*>(w1 + (((size_t)t2*4+ct)*64 + lane)*8);
    }
    // t1 = 2k+1 (channels 32..63)
    #pragma unroll
    for (int ct=0;ct<4;ct++){
      acc[0][ct] = __builtin_amdgcn_mfma_f32_16x16x32_bf16(ac[1], b1[ct], acc[0][ct], 0,0,0);
      acc[1][ct] = __builtin_amdgcn_mfma_f32_16x16x32_bf16(ac[3], b1[ct], acc[1][ct], 0,0,0);
    }
    if (k+1 < KNBR){
      int t3 = 2*k + 3;
      #pragma unroll
      for (int ct=0;ct<4;ct++)
        b1[ct] = *reinterpret_cast<const bf16x8*>(w1 + (((size_t)t3*4+ct)*64 + lane)*8);
    }
    // fence: keep all B-issues of this iter before the A-issue below
    __builtin_amdgcn_sched_barrier(0);
    bf16x8 at0 = ac[0], at1 = ac[1], at2 = ac[2], at3 = ac[3];
    if (k+2 < KNBR){
      const u16* rr0 = sb + (size_t)idx0[k+2]*64 + qoff;
      const u16* rr1 = sb + (size_t)idx1[k+2]*64 + qoff;
      at0 = *reinterpret_cast<const bf16x8*>(rr0);
      at1 = *reinterpret_cast<const bf16x8*>(rr0 + 32);
      at2 = *reinterpret_cast<const bf16x8*>(rr1);
      at3 = *reinterpret_cast<const bf16x8*>(rr1 + 32);
    }
    ac[0]=an[0]; ac[1]=an[1]; ac[2]=an[2]; ac[3]=an[3];
    an[0]=at0;  an[1]=at1;  an[2]=at2;  an[3]=at3;
  }
  __syncthreads();   // s_idx dead; reuse LDS for epilogue tiles

  // lrelu -> bf16 tile in LDS (C-layout -> A-layout round trip); wave-private tile
  u16* sa = s_a + wv*32*APAD;
  #pragma unroll
  for (int mt=0;mt<2;mt++){
    #pragma unroll
    for (int ct=0;ct<4;ct++){
      #pragma unroll
      for (int i=0;i<4;i++){
        int rl = mt*16 + quad*4 + i;
        sa[rl*APAD + ct*16 + m] = f2bf(lrelu(acc[mt][ct][i]));
      }
    }
  }
  __syncthreads();

  f32x4 d[2][4];
  #pragma unroll
  for (int mt=0;mt<2;mt++)
    #pragma unroll
    for (int i=0;i<4;i++) d[mt][i] = zz;
  #pragma unroll
  for (int c=0;c<2;c++){
    #pragma unroll
    for (int mt=0;mt<2;mt++){
      bf16x8 a = *reinterpret_cast<const bf16x8*>(&sa[(mt*16 + m)*APAD + c*32 + qoff]);
      #pragma unroll
      for (int ct=0;ct<4;ct++){
        bf16x8 b = *reinterpret_cast<const bf16x8*>(w2 + (((size_t)c*4+ct)*64 + lane)*8);
        d[mt][ct] = __builtin_amdgcn_mfma_f32_16x16x32_bf16(a, b, d[mt][ct], 0,0,0);
      }
    }
  }
  #pragma unroll
  for (int mt=0;mt<2;mt++){
    #pragma unroll
    for (int ct=0;ct<4;ct++){
      #pragma unroll
      for (int i=0;i<4;i++){
        int row = row0 + wrow + mt*16 + quad*4 + i;
        if (row < NNODES){
          u[(size_t)row*128 + gh*64 + ct*16 + m] = f2bf(lrelu(d[mt][ct][i]));
        }
      }
    }
  }
}

// bg = gather(u[:,:64]) @ w3g ; bh = gather(u[:,64:]) @ w3h ;
// y = x_prev * exp(2*sigmoid(bg)-1) + bh -> out fp32; optionally y -> yb bf16.
// 4 waves: (gh, rhalf); 32 rows/wave (2 M-tiles), one matrix per wave.
__global__ __launch_bounds__(256,4) void conv2_coupling(
    const u16* __restrict__ ub,
    const int* __restrict__ nbr,
    const u16* __restrict__ wbg, const u16* __restrict__ wbh,
    const float* __restrict__ x, int xcol0,
    float* __restrict__ out, int ycol0,
    u16* __restrict__ yb, int write_yb)
{
  extern __shared__ char smem[];
  int*   s_idx = (int*)smem;     // [MR*KNBR] = 6912 B (k-loop)
  float* s_bh  = (float*)smem;   // [MR*65]   = 16640 B (epilogue)

  int tid = threadIdx.x;
  int row0 = blockIdx.x * MR;
  for (int i = tid; i < MR*KNBR; i += 256){
    int r = i / KNBR, kk = i - r*KNBR;
    int row = row0 + r;
    s_idx[i] = (row < NNODES) ? nbr[row*KNBR + kk] : 0;
  }
  __syncthreads();

  int lane = tid & 63;
  int wv = tid >> 6;
  int gh = wv >> 1;                 // 0 = g matrix, 1 = h matrix
  int rhalf = wv & 1;               // which 32-row half
  int quad = lane >> 4, m = lane & 15;
  int qoff = quad * 8;
  int wrow = rhalf * 32;
  const int* idx0 = &s_idx[(wrow + m)*KNBR];
  const int* idx1 = &s_idx[(wrow + 16 + m)*KNBR];
  const u16* wb = gh ? wbh : wbg;
  const size_t ghoff = (size_t)gh * 64;   // h reads ub cols 64..127

  f32x4 acc[2][4];
  f32x4 zz = {0.f,0.f,0.f,0.f};
  #pragma unroll
  for (int mt=0;mt<2;mt++)
    #pragma unroll
    for (int i=0;i<4;i++) acc[mt][i] = zz;

  bf16x8 ac[4], an[4], b0[4], b1[4];
  {
    // prologue order: A(0), B(0), B(1), A(1)
    const u16* r0 = ub + (size_t)idx0[0]*128 + ghoff + qoff;
    const u16* r1 = ub + (size_t)idx1[0]*128 + ghoff + qoff;
    ac[0] = *reinterpret_cast<const bf16x8*>(r0);
    ac[1] = *reinterpret_cast<const bf16x8*>(r0 + 32);
    ac[2] = *reinterpret_cast<const bf16x8*>(r1);
    ac[3] = *reinterpret_cast<const bf16x8*>(r1 + 32);
    #pragma unroll
    for (int ct=0;ct<4;ct++){
      b0[ct] = *reinterpret_cast<const bf16x8*>(wb + (((size_t)0*4+ct)*64 + lane)*8);
      b1[ct] = *reinterpret_cast<const bf16x8*>(wb + (((size_t)1*4+ct)*64 + lane)*8);
    }
    const u16* s0 = ub + (size_t)idx0[1]*128 + ghoff + qoff;
    const u16* s1 = ub + (size_t)idx1[1]*128 + ghoff + qoff;
    an[0] = *reinterpret_cast<const bf16x8*>(s0);
    an[1] = *reinterpret_cast<const bf16x8*>(s0 + 32);
    an[2] = *reinterpret_cast<const bf16x8*>(s1);
    an[3] = *reinterpret_cast<const bf16x8*>(s1 + 32);
  }

  #pragma unroll
  for (int k=0;k<KNBR;k++){
    // t0 = 2k (channels 0..31)
    #pragma unroll
    for (int ct=0;ct<4;ct++){
      acc[0][ct] = __builtin_amdgcn_mfma_f32_16x16x32_bf16(ac[0], b0[ct], acc[0][ct], 0,0,0);
      acc[1][ct] = __builtin_amdgcn_mfma_f32_16x16x32_bf16(ac[2], b0[ct], acc[1][ct], 0,0,0);
    }
    if (k+1 < KNBR){
      int t2 = 2*k + 2;
      #pragma unroll
      for (int ct=0;ct<4;ct++)
        b0[ct] = *reinterpret_cast<const bf16x8*>(wb + (((size_t)t2*4+ct)*64 + lane)*8);
    }
    // t1 = 2k+1 (channels 32..63)
    #pragma unroll
    for (int ct=0;ct<4;ct++){
      acc[0][ct] = __builtin_amdgcn_mfma_f32_16x16x32_bf16(ac[1], b1[ct], acc[0][ct], 0,0,0);
      acc[1][ct] = __builtin_amdgcn_mfma_f32_16x16x32_bf16(ac[3], b1[ct], acc[1][ct], 0,0,0);
    }
    if (k+1 < KNBR){
      int t3 = 2*k + 3;
      #pragma unroll
      for (int ct=0;ct<4;ct++)
        b1[ct] = *reinterpret_cast<const bf16x8*>(wb + (((size_t)t3*4+ct)*64 + lane)*8);
    }
    // fence: keep all B-issues of this iter before the A-issue below
    __builtin_amdgcn_sched_barrier(0);
    bf16x8 at0 = ac[0], at1 = ac[1], at2 = ac[2], at3 = ac[3];
    if (k+2 < KNBR){
      const u16* rr0 = ub + (size_t)idx0[k+2]*128 + ghoff + qoff;
      const u16* rr1 = ub + (size_t)idx1[k+2]*128 + ghoff + qoff;
      at0 = *reinterpret_cast<const bf16x8*>(rr0);
      at1 = *reinterpret_cast<const bf16x8*>(rr0 + 32);
      at2 = *reinterpret_cast<const bf16x8*>(rr1);
      at3 = *reinterpret_cast<const bf16x8*>(rr1 + 32);
    }
    ac[0]=an[0]; ac[1]=an[1]; ac[2]=an[2]; ac[3]=an[3];
    an[0]=at0;  an[1]=at1;  an[2]=at2;  an[3]=at3;
  }

  // ---- coupling epilogue: h-waves publish bh via LDS; g-waves combine ----
  float xv[2][4][4];
  if (gh == 0){
    #pragma unroll
    for (int mt=0;mt<2;mt++){
      #pragma unroll
      for (int ct=0;ct<4;ct++){
        #pragma unroll
        for (int i=0;i<4;i++){
          int row = row0 + wrow + mt*16 + quad*4 + i;
          xv[mt][ct][i] = (row < NNODES) ? x[(size_t)row*LDX + xcol0 + ct*16 + m] : 0.f;
        }
      }
    }
  }
  __syncthreads();   // all s_idx reads done; safe to overwrite smem
  if (gh == 1){
    #pragma unroll
    for (int mt=0;mt<2;mt++){
      #pragma unroll
      for (int ct=0;ct<4;ct++){
        #pragma unroll
        for (int i=0;i<4;i++){
          int rl = wrow + mt*16 + quad*4 + i;
          s_bh[rl*65 + ct*16 + m] = acc[mt][ct][i];
        }
      }
    }
  }
  __syncthreads();
  if (gh == 0){
    #pragma unroll
    for (int mt=0;mt<2;mt++){
      #pragma unroll
      for (int ct=0;ct<4;ct++){
        #pragma unroll
        for (int i=0;i<4;i++){
          int rl = wrow + mt*16 + quad*4 + i;
          int row = row0 + rl;
          if (row < NNODES){
            int col = ct*16 + m;
            float bg = acc[mt][ct][i];
            float bh = s_bh[rl*65 + col];
            float s = 1.f/(1.f + __expf(-bg));
            s = __expf(2.f*s - 1.f);
            float y = xv[mt][ct][i]*s + bh;
            out[(size_t)row*LDX + ycol0 + col] = y;
            if (write_yb) yb[(size_t)row*64 + col] = f2bf(y);
          }
        }
      }
    }
  }
}

extern "C" void kernel_launch(void* const* d_in, const int* in_sizes, int n_in,
                              void* d_out, int out_size, void* d_ws, size_t ws_size,
                              hipStream_t stream)
{
  const float* x   = (const float*)d_in[0];
  const int*   nbr = (const int*)d_in[1];
  const float* g1_w1=(const float*)d_in[2],  *g1_w2=(const float*)d_in[3],  *g1_w3=(const float*)d_in[4];
  const float* g2_w1=(const float*)d_in[5],  *g2_w2=(const float*)d_in[6],  *g2_w3=(const float*)d_in[7];
  const float* h1_w1=(const float*)d_in[8],  *h1_w2=(const float*)d_in[9],  *h1_w3=(const float*)d_in[10];
  const float* h2_w1=(const float*)d_in[11], *h2_w2=(const float*)d_in[12], *h2_w3=(const float*)d_in[13];
  float* out = (float*)d_out;
  u16* ws = (u16*)d_ws;

  const size_t WBB = (size_t)54*4*64*8;  // 1728-row weights (bf16 frags)
  const size_t WBS = (size_t)2*4*64*8;   // 64-row weights
  u16* p = ws;
  u16* wb_g2_1=p; p+=WBB;  u16* wb_h2_1=p; p+=WBB;
  u16* wb_g2_2=p; p+=WBS;  u16* wb_h2_2=p; p+=WBS;
  u16* wb_g2_3=p; p+=WBB;  u16* wb_h2_3=p; p+=WBB;
  u16* wb_g1_1=p; p+=WBB;  u16* wb_h1_1=p; p+=WBB;
  u16* wb_g1_2=p; p+=WBS;  u16* wb_h1_2=p; p+=WBS;
  u16* wb_g1_3=p; p+=WBB;  u16* wb_h1_3=p; p+=WBB;
  u16* ub = p; p += (size_t)NNODES*128;   // interleaved [g|h] bf16
  u16* sb = p; p += (size_t)NNODES*64;    // gather source (x2 bf16, then y1 bf16)

  reformat_w<<<54,256,0,stream>>>(g2_w1, wb_g2_1, 54);
  reformat_w<<<54,256,0,stream>>>(h2_w1, wb_h2_1, 54);
  reformat_w<<<2,256,0,stream>>>(g2_w2, wb_g2_2, 2);
  reformat_w<<<2,256,0,stream>>>(h2_w2, wb_h2_2, 2);
  reformat_w<<<54,256,0,stream>>>(g2_w3, wb_g2_3, 54);
  reformat_w<<<54,256,0,stream>>>(h2_w3, wb_h2_3, 54);
  reformat_w<<<54,256,0,stream>>>(g1_w1, wb_g1_1, 54);
  reformat_w<<<54,256,0,stream>>>(h1_w1, wb_h1_1, 54);
  reformat_w<<<2,256,0,stream>>>(g1_w2, wb_g1_2, 2);
  reformat_w<<<2,256,0,stream>>>(h1_w2, wb_h1_2, 2);
  reformat_w<<<54,256,0,stream>>>(g1_w3, wb_g1_3, 54);
  reformat_w<<<54,256,0,stream>>>(h1_w3, wb_h1_3, 54);

  conv_x2<<<(NNODES*64/8 + 255)/256, 256, 0, stream>>>(x, sb);

  int nblk = (NNODES + MR - 1)/MR;        // 2344
  size_t c1_lds = (size_t)4*32*APAD*2;    // 18432 B (>= s_idx 6912 B)
  size_t c2_lds = (size_t)MR*65*4;        // 16640 B (>= s_idx 6912 B)

  // Phase A: sb = x2(bf16); y1 -> out cols 0..63 + sb(bf16)
  conv1_fused<<<nblk,256,c1_lds,stream>>>(sb, nbr, wb_g2_1, wb_h2_1, wb_g2_2, wb_h2_2, ub);
  conv2_coupling<<<nblk,256,c2_lds,stream>>>(ub, nbr, wb_g2_3, wb_h2_3, x, 0, out, 0, sb, 1);
  // Phase B: sb = y1(bf16); y2 -> out cols 64..127
  conv1_fused<<<nblk,256,c1_lds,stream>>>(sb, nbr, wb_g1_1, wb_h1_1, wb_g1_2, wb_h1_2, ub);
  conv2_coupling<<<nblk,256,c2_lds,stream>>>(ub, nbr, wb_g1_3, wb_h1_3, x, 64, out, 64, sb, 0);
}

// Round 3
// 790.928 us; speedup vs baseline: 1.3900x; 1.2238x over previous
//
#include <hip/hip_runtime.h>
#include <stdint.h>

typedef unsigned short u16;
typedef __bf16 bf16x8 __attribute__((ext_vector_type(8)));
typedef float f32x4 __attribute__((ext_vector_type(4)));

#define NNODES 150000
#define KNBR 27
#define LDX 128
#define MR 64      // rows per block; 4 waves x 16 rows, each wave computes g AND h
#define APAD 72    // epilogue LDS row stride (u16)
#define WSU 8192   // u16 per 16KB weight stage buffer

#define WAITVM(N) asm volatile("s_waitcnt vmcnt(" #N ")" ::: "memory")
#define LGKM0()   asm volatile("s_waitcnt lgkmcnt(0)" ::: "memory")

static __device__ __forceinline__ void gl_lds16(const u16* g, u16* l){
  __builtin_amdgcn_global_load_lds((const __attribute__((address_space(1))) void*)g,
                                   (__attribute__((address_space(3))) void*)l, 16, 0, 0);
}

static __device__ __forceinline__ u16 f2bf(float f){
  union { float f; uint32_t i; } v; v.f = f;
  uint32_t x = v.i;
  uint32_t r = (x + 0x7fffu + ((x >> 16) & 1u)) >> 16;  // RNE
  return (u16)r;
}
static __device__ __forceinline__ float lrelu(float v){ return v >= 0.f ? v : 0.2f*v; }

// fp32 weight (krows x 64) -> bf16 MFMA B-fragment order
__global__ void reformat_w(const float* __restrict__ src, u16* __restrict__ dst, int ksteps){
  int idx = blockIdx.x*256 + threadIdx.x;
  int total = ksteps*4*64;
  if (idx >= total) return;
  int lane = idx & 63;
  int ctile = (idx >> 6) & 3;
  int t = idx >> 8;
  int quad = lane >> 4, m = lane & 15;
  union { u16 h[8]; float4 v; } tmp;
  const float* s = src + ((size_t)(t*32 + quad*8))*64 + ctile*16 + m;
  #pragma unroll
  for (int j=0;j<8;j++) tmp.h[j] = f2bf(s[j*64]);
  *reinterpret_cast<float4*>(dst + (size_t)idx*8) = tmp.v;
}

// x cols 64..127 (fp32, LDX stride) -> bf16 table sb (N x 64)
__global__ void conv_x2(const float* __restrict__ x, u16* __restrict__ sb){
  int idx = blockIdx.x*256 + threadIdx.x;
  int e = idx*8;
  if (e >= NNODES*64) return;
  int row = e >> 6, col = e & 63;
  const float* s = x + (size_t)row*LDX + 64 + col;
  float4 a = *reinterpret_cast<const float4*>(s);
  float4 b = *reinterpret_cast<const float4*>(s+4);
  union { u16 h[8]; float4 v; } t;
  t.h[0]=f2bf(a.x); t.h[1]=f2bf(a.y); t.h[2]=f2bf(a.z); t.h[3]=f2bf(a.w);
  t.h[4]=f2bf(b.x); t.h[5]=f2bf(b.y); t.h[6]=f2bf(b.z); t.h[7]=f2bf(b.w);
  *reinterpret_cast<float4*>(sb + e) = t.v;
}

// u[:,0:64] = lrelu(lrelu(gather(sb) @ w1g) @ w2g); u[:,64:128] = h-version.
// 4 waves x 16 rows; each wave computes BOTH matrices (no duplicate gathers).
// Weights staged into LDS (global_load_lds, double-buffered, counted vmcnt);
// A-gathers register-pipelined depth-3.
__global__ __launch_bounds__(256,4) void conv1_fused(
    const u16* __restrict__ sb,
    const int* __restrict__ nbr,
    const u16* __restrict__ wb1g, const u16* __restrict__ wb1h,
    const u16* __restrict__ wb2g, const u16* __restrict__ wb2h,
    u16* __restrict__ u)
{
  extern __shared__ char smem[];
  u16* ws    = (u16*)smem;                    // [2][WSU] weight stages = 32768 B
  int* s_idx = (int*)(smem + 2*WSU*2);        // [MR*KNBR] = 6912 B
  u16* sa    = (u16*)smem;                    // epilogue alias (18432 B)

  int tid = threadIdx.x;
  int row0 = blockIdx.x * MR;
  for (int i = tid; i < MR*KNBR; i += 256){
    int r = i / KNBR, kk = i - r*KNBR;
    int row = row0 + r;
    s_idx[i] = (row < NNODES) ? nbr[row*KNBR + kk] : 0;
  }
  __syncthreads();

  int lane = tid & 63;
  int wv = tid >> 6;
  int quad = lane >> 4, m = lane & 15;
  int qoff = quad * 8;
  int tt_w = wv >> 1, mat_w = wv & 1;         // this wave's staging slab group
  const u16* wsrc = mat_w ? wb1h : wb1g;
  const int* idx = &s_idx[(wv*16 + m)*KNBR];

  f32x4 acc[2][4];
  f32x4 zz = {0.f,0.f,0.f,0.f};
  #pragma unroll
  for (int mt2=0;mt2<2;mt2++)
    #pragma unroll
    for (int i=0;i<4;i++) acc[mt2][i] = zz;

  bf16x8 as[3][2];

  // stage weight slices for k-step s into ws[s&1]: wave handles (tt_w, mat_w), ct 0..3
  #define STAGE_W1(s) { \
    u16* dst_ = ws + ((s)&1)*WSU + (tt_w*2+mat_w)*2048; \
    const u16* src_ = wsrc + ((size_t)(2*(s)+tt_w))*2048 + (size_t)lane*8; \
    _Pragma("unroll") \
    for (int ct_=0; ct_<4; ct_++) gl_lds16(src_ + ct_*512, dst_ + ct_*512); }

  #define LOAD_A1(s, d0, d1) { \
    const u16* r_ = sb + (size_t)idx[s]*64 + qoff; \
    d0 = *reinterpret_cast<const bf16x8*>(r_); \
    d1 = *reinterpret_cast<const bf16x8*>(r_ + 32); }

  // prologue: WS0, A0 | WS1, A1 | A2  (sched_barrier pins group order)
  STAGE_W1(0); __builtin_amdgcn_sched_barrier(0);
  LOAD_A1(0, as[0][0], as[0][1]); __builtin_amdgcn_sched_barrier(0);
  STAGE_W1(1); __builtin_amdgcn_sched_barrier(0);
  LOAD_A1(1, as[1][0], as[1][1]); __builtin_amdgcn_sched_barrier(0);
  LOAD_A1(2, as[2][0], as[2][1]);

  #pragma unroll
  for (int k=0;k<KNBR;k++){
    // conservative counted waits (never force pending A-stages beyond need):
    if (k <= 1)       { WAITVM(8); }
    else if (k <= 24) { WAITVM(6); }
    else if (k == 25) { WAITVM(4); }
    else              { WAITVM(0); }
    __builtin_amdgcn_s_barrier();      // all waves' WS_k slabs visible

    const u16* wsb = ws + (k&1)*WSU;
    #pragma unroll
    for (int tt=0;tt<2;tt++){
      bf16x8 af = as[k%3][tt];
      #pragma unroll
      for (int mt2=0;mt2<2;mt2++){
        #pragma unroll
        for (int ct=0;ct<4;ct++){
          bf16x8 b = *reinterpret_cast<const bf16x8*>(wsb + ((tt*2+mt2)*4+ct)*512 + (size_t)lane*8);
          acc[mt2][ct] = __builtin_amdgcn_mfma_f32_16x16x32_bf16(af, b, acc[mt2][ct], 0,0,0);
        }
      }
    }
    LGKM0();
    __builtin_amdgcn_s_barrier();      // all waves done reading ws[k&1]
    if (k+2 < KNBR) { STAGE_W1(k+2); }
    __builtin_amdgcn_sched_barrier(0);
    if (k+3 < KNBR) { LOAD_A1(k+3, as[(k+3)%3][0], as[(k+3)%3][1]); }
  }

  // epilogue: wave-private LDS transpose (ws dead after last barrier)
  #pragma unroll
  for (int mt2=0;mt2<2;mt2++){
    #pragma unroll
    for (int ct=0;ct<4;ct++){
      #pragma unroll
      for (int i=0;i<4;i++){
        int rl = wv*16 + quad*4 + i;
        sa[mt2*MR*APAD + rl*APAD + ct*16 + m] = f2bf(lrelu(acc[mt2][ct][i]));
      }
    }
  }
  // wave-private tile: no cross-wave barrier needed
  f32x4 d[2][4];
  #pragma unroll
  for (int mt2=0;mt2<2;mt2++)
    #pragma unroll
    for (int i=0;i<4;i++) d[mt2][i] = zz;
  #pragma unroll
  for (int c=0;c<2;c++){
    #pragma unroll
    for (int mt2=0;mt2<2;mt2++){
      bf16x8 a = *reinterpret_cast<const bf16x8*>(&sa[mt2*MR*APAD + (wv*16 + m)*APAD + c*32 + qoff]);
      #pragma unroll
      for (int ct=0;ct<4;ct++){
        const u16* wp = (mt2 ? wb2h : wb2g) + (((size_t)c*4+ct)*64 + lane)*8;
        bf16x8 b = *reinterpret_cast<const bf16x8*>(wp);
        d[mt2][ct] = __builtin_amdgcn_mfma_f32_16x16x32_bf16(a, b, d[mt2][ct], 0,0,0);
      }
    }
  }
  #pragma unroll
  for (int mt2=0;mt2<2;mt2++){
    #pragma unroll
    for (int ct=0;ct<4;ct++){
      #pragma unroll
      for (int i=0;i<4;i++){
        int row = row0 + wv*16 + quad*4 + i;
        if (row < NNODES){
          u[(size_t)row*128 + mt2*64 + ct*16 + m] = f2bf(lrelu(d[mt2][ct][i]));
        }
      }
    }
  }
  #undef STAGE_W1
  #undef LOAD_A1
}

// bg = gather(u[:,:64]) @ w3g ; bh = gather(u[:,64:]) @ w3h ;
// y = x_prev * exp(2*sigmoid(bg)-1) + bh -> out fp32; optionally y -> yb bf16.
// 4 waves x 16 rows, both matrices per wave (coupling stays in-register).
// Weights LDS-staged; full-256B-row gathers register-pipelined depth-2.
__global__ __launch_bounds__(256,4) void conv2_coupling(
    const u16* __restrict__ ub,
    const int* __restrict__ nbr,
    const u16* __restrict__ wbg, const u16* __restrict__ wbh,
    const float* __restrict__ x, int xcol0,
    float* __restrict__ out, int ycol0,
    u16* __restrict__ yb, int write_yb)
{
  extern __shared__ char smem[];
  u16* ws    = (u16*)smem;                    // [2][WSU] = 32768 B
  int* s_idx = (int*)(smem + 2*WSU*2);        // [MR*KNBR] = 6912 B

  int tid = threadIdx.x;
  int row0 = blockIdx.x * MR;
  for (int i = tid; i < MR*KNBR; i += 256){
    int r = i / KNBR, kk = i - r*KNBR;
    int row = row0 + r;
    s_idx[i] = (row < NNODES) ? nbr[row*KNBR + kk] : 0;
  }
  __syncthreads();

  int lane = tid & 63;
  int wv = tid >> 6;
  int quad = lane >> 4, m = lane & 15;
  int qoff = quad * 8;
  int tt_w = wv >> 1, mat_w = wv & 1;
  const u16* wsrc = mat_w ? wbh : wbg;
  const int* idx = &s_idx[(wv*16 + m)*KNBR];

  f32x4 accg[4], acch[4];
  f32x4 zz = {0.f,0.f,0.f,0.f};
  #pragma unroll
  for (int i=0;i<4;i++){ accg[i]=zz; acch[i]=zz; }

  bf16x8 as[2][4];

  #define STAGE_W2(s) { \
    u16* dst_ = ws + ((s)&1)*WSU + (tt_w*2+mat_w)*2048; \
    const u16* src_ = wsrc + ((size_t)(2*(s)+tt_w))*2048 + (size_t)lane*8; \
    _Pragma("unroll") \
    for (int ct_=0; ct_<4; ct_++) gl_lds16(src_ + ct_*512, dst_ + ct_*512); }

  #define LOAD_A2(s, d0, d1, d2, d3) { \
    const u16* r_ = ub + (size_t)idx[s]*128 + qoff; \
    d0 = *reinterpret_cast<const bf16x8*>(r_); \
    d1 = *reinterpret_cast<const bf16x8*>(r_ + 32); \
    d2 = *reinterpret_cast<const bf16x8*>(r_ + 64); \
    d3 = *reinterpret_cast<const bf16x8*>(r_ + 96); }

  STAGE_W2(0); __builtin_amdgcn_sched_barrier(0);
  LOAD_A2(0, as[0][0], as[0][1], as[0][2], as[0][3]); __builtin_amdgcn_sched_barrier(0);
  STAGE_W2(1); __builtin_amdgcn_sched_barrier(0);
  LOAD_A2(1, as[1][0], as[1][1], as[1][2], as[1][3]);

  #pragma unroll
  for (int k=0;k<KNBR;k++){
    if (k <= 25) { WAITVM(8); }
    else         { WAITVM(0); }
    __builtin_amdgcn_s_barrier();

    const u16* wsb = ws + (k&1)*WSU;
    #pragma unroll
    for (int tt=0;tt<2;tt++){
      bf16x8 ag = as[k&1][tt];       // g cols, k-half tt
      bf16x8 ah = as[k&1][2+tt];     // h cols
      #pragma unroll
      for (int ct=0;ct<4;ct++){
        bf16x8 bg = *reinterpret_cast<const bf16x8*>(wsb + ((tt*2+0)*4+ct)*512 + (size_t)lane*8);
        accg[ct] = __builtin_amdgcn_mfma_f32_16x16x32_bf16(ag, bg, accg[ct], 0,0,0);
      }
      #pragma unroll
      for (int ct=0;ct<4;ct++){
        bf16x8 bh = *reinterpret_cast<const bf16x8*>(wsb + ((tt*2+1)*4+ct)*512 + (size_t)lane*8);
        acch[ct] = __builtin_amdgcn_mfma_f32_16x16x32_bf16(ah, bh, acch[ct], 0,0,0);
      }
    }
    LGKM0();
    __builtin_amdgcn_s_barrier();
    if (k+2 < KNBR) { STAGE_W2(k+2); }
    __builtin_amdgcn_sched_barrier(0);
    if (k+2 < KNBR) { LOAD_A2(k+2, as[k&1][0], as[k&1][1], as[k&1][2], as[k&1][3]); }
  }

  // coupling epilogue: bg and bh live in the same wave — no LDS exchange
  #pragma unroll
  for (int ct=0;ct<4;ct++){
    #pragma unroll
    for (int i=0;i<4;i++){
      int row = row0 + wv*16 + quad*4 + i;
      if (row < NNODES){
        int col = ct*16 + m;
        float bg = accg[ct][i];
        float bh = acch[ct][i];
        float s = 1.f/(1.f + __expf(-bg));
        s = __expf(2.f*s - 1.f);
        float xv = x[(size_t)row*LDX + xcol0 + col];
        float y = xv*s + bh;
        out[(size_t)row*LDX + ycol0 + col] = y;
        if (write_yb) yb[(size_t)row*64 + col] = f2bf(y);
      }
    }
  }
  #undef STAGE_W2
  #undef LOAD_A2
}

extern "C" void kernel_launch(void* const* d_in, const int* in_sizes, int n_in,
                              void* d_out, int out_size, void* d_ws, size_t ws_size,
                              hipStream_t stream)
{
  const float* x   = (const float*)d_in[0];
  const int*   nbr = (const int*)d_in[1];
  const float* g1_w1=(const float*)d_in[2],  *g1_w2=(const float*)d_in[3],  *g1_w3=(const float*)d_in[4];
  const float* g2_w1=(const float*)d_in[5],  *g2_w2=(const float*)d_in[6],  *g2_w3=(const float*)d_in[7];
  const float* h1_w1=(const float*)d_in[8],  *h1_w2=(const float*)d_in[9],  *h1_w3=(const float*)d_in[10];
  const float* h2_w1=(const float*)d_in[11], *h2_w2=(const float*)d_in[12], *h2_w3=(const float*)d_in[13];
  float* out = (float*)d_out;
  u16* ws = (u16*)d_ws;

  const size_t WBB = (size_t)54*4*64*8;  // 1728-row weights (bf16 frags)
  const size_t WBS = (size_t)2*4*64*8;   // 64-row weights
  u16* p = ws;
  u16* wb_g2_1=p; p+=WBB;  u16* wb_h2_1=p; p+=WBB;
  u16* wb_g2_2=p; p+=WBS;  u16* wb_h2_2=p; p+=WBS;
  u16* wb_g2_3=p; p+=WBB;  u16* wb_h2_3=p; p+=WBB;
  u16* wb_g1_1=p; p+=WBB;  u16* wb_h1_1=p; p+=WBB;
  u16* wb_g1_2=p; p+=WBS;  u16* wb_h1_2=p; p+=WBS;
  u16* wb_g1_3=p; p+=WBB;  u16* wb_h1_3=p; p+=WBB;
  u16* ub = p; p += (size_t)NNODES*128;   // interleaved [g|h] bf16
  u16* sb = p; p += (size_t)NNODES*64;    // gather source (x2 bf16, then y1 bf16)

  reformat_w<<<54,256,0,stream>>>(g2_w1, wb_g2_1, 54);
  reformat_w<<<54,256,0,stream>>>(h2_w1, wb_h2_1, 54);
  reformat_w<<<2,256,0,stream>>>(g2_w2, wb_g2_2, 2);
  reformat_w<<<2,256,0,stream>>>(h2_w2, wb_h2_2, 2);
  reformat_w<<<54,256,0,stream>>>(g2_w3, wb_g2_3, 54);
  reformat_w<<<54,256,0,stream>>>(h2_w3, wb_h2_3, 54);
  reformat_w<<<54,256,0,stream>>>(g1_w1, wb_g1_1, 54);
  reformat_w<<<54,256,0,stream>>>(h1_w1, wb_h1_1, 54);
  reformat_w<<<2,256,0,stream>>>(g1_w2, wb_g1_2, 2);
  reformat_w<<<2,256,0,stream>>>(h1_w2, wb_h1_2, 2);
  reformat_w<<<54,256,0,stream>>>(g1_w3, wb_g1_3, 54);
  reformat_w<<<54,256,0,stream>>>(h1_w3, wb_h1_3, 54);

  conv_x2<<<(NNODES*64/8 + 255)/256, 256, 0, stream>>>(x, sb);

  int nblk = (NNODES + MR - 1)/MR;        // 2344
  size_t lds_sz = (size_t)2*WSU*2 + (size_t)MR*KNBR*4;  // 32768 + 6912 = 39680 B

  // Phase A: sb = x2(bf16); y1 -> out cols 0..63 + sb(bf16)
  conv1_fused<<<nblk,256,lds_sz,stream>>>(sb, nbr, wb_g2_1, wb_h2_1, wb_g2_2, wb_h2_2, ub);
  conv2_coupling<<<nblk,256,lds_sz,stream>>>(ub, nbr, wb_g2_3, wb_h2_3, x, 0, out, 0, sb, 1);
  // Phase B: sb = y1(bf16); y2 -> out cols 64..127
  conv1_fused<<<nblk,256,lds_sz,stream>>>(sb, nbr, wb_g1_1, wb_h1_1, wb_g1_2, wb_h1_2, ub);
  conv2_coupling<<<nblk,256,lds_sz,stream>>>(ub, nbr, wb_g1_3, wb_h1_3, x, 64, out, 64, sb, 0);
}

// Round 4
// 789.430 us; speedup vs baseline: 1.3926x; 1.0019x over previous
//
#include <hip/hip_runtime.h>
#include <stdint.h>

typedef unsigned short u16;
typedef __bf16 bf16x8 __attribute__((ext_vector_type(8)));
typedef float f32x4 __attribute__((ext_vector_type(4)));

#define NNODES 150000
#define KNBR 27
#define LDX 128
#define MR 64      // rows per block; 4 waves x 16 rows, each wave computes g AND h
#define APAD 72    // epilogue LDS row stride (u16)
#define WSU 8192   // u16 per 16KB weight stage buffer

#define WAITVM(N) asm volatile("s_waitcnt vmcnt(" #N ")" ::: "memory")

static __device__ __forceinline__ void gl_lds16(const u16* g, u16* l){
  __builtin_amdgcn_global_load_lds((const __attribute__((address_space(1))) void*)g,
                                   (__attribute__((address_space(3))) void*)l, 16, 0, 0);
}

static __device__ __forceinline__ u16 f2bf(float f){
  union { float f; uint32_t i; } v; v.f = f;
  uint32_t x = v.i;
  uint32_t r = (x + 0x7fffu + ((x >> 16) & 1u)) >> 16;  // RNE
  return (u16)r;
}
static __device__ __forceinline__ float lrelu(float v){ return v >= 0.f ? v : 0.2f*v; }

// fp32 weight (krows x 64) -> bf16 MFMA B-fragment order
__global__ void reformat_w(const float* __restrict__ src, u16* __restrict__ dst, int ksteps){
  int idx = blockIdx.x*256 + threadIdx.x;
  int total = ksteps*4*64;
  if (idx >= total) return;
  int lane = idx & 63;
  int ctile = (idx >> 6) & 3;
  int t = idx >> 8;
  int quad = lane >> 4, m = lane & 15;
  union { u16 h[8]; float4 v; } tmp;
  const float* s = src + ((size_t)(t*32 + quad*8))*64 + ctile*16 + m;
  #pragma unroll
  for (int j=0;j<8;j++) tmp.h[j] = f2bf(s[j*64]);
  *reinterpret_cast<float4*>(dst + (size_t)idx*8) = tmp.v;
}

// x cols 64..127 (fp32, LDX stride) -> bf16 table sb (N x 64)
__global__ void conv_x2(const float* __restrict__ x, u16* __restrict__ sb){
  int idx = blockIdx.x*256 + threadIdx.x;
  int e = idx*8;
  if (e >= NNODES*64) return;
  int row = e >> 6, col = e & 63;
  const float* s = x + (size_t)row*LDX + 64 + col;
  float4 a = *reinterpret_cast<const float4*>(s);
  float4 b = *reinterpret_cast<const float4*>(s+4);
  union { u16 h[8]; float4 v; } t;
  t.h[0]=f2bf(a.x); t.h[1]=f2bf(a.y); t.h[2]=f2bf(a.z); t.h[3]=f2bf(a.w);
  t.h[4]=f2bf(b.x); t.h[5]=f2bf(b.y); t.h[6]=f2bf(b.z); t.h[7]=f2bf(b.w);
  *reinterpret_cast<float4*>(sb + e) = t.v;
}

// u[:,0:64] = lrelu(lrelu(gather(sb) @ w1g) @ w2g); u[:,64:128] = h-version.
// 4 waves x 16 rows; each wave computes BOTH matrices (no duplicate gathers).
// Single barrier/iter: WAITVM -> barrier -> STAGE(k+1) -> MFMA(k) -> LOAD A(k+3).
__global__ __launch_bounds__(256,4) void conv1_fused(
    const u16* __restrict__ sb,
    const int* __restrict__ nbr,
    const u16* __restrict__ wb1g, const u16* __restrict__ wb1h,
    const u16* __restrict__ wb2g, const u16* __restrict__ wb2h,
    u16* __restrict__ u)
{
  extern __shared__ char smem[];
  u16* ws    = (u16*)smem;                    // [2][WSU] weight stages = 32768 B
  int* s_idx = (int*)(smem + 2*WSU*2);        // [MR*KNBR] = 6912 B
  u16* sa    = (u16*)smem;                    // epilogue alias (36864 B, whole smem)

  int tid = threadIdx.x;
  int row0 = blockIdx.x * MR;
  for (int i = tid; i < MR*KNBR; i += 256){
    int r = i / KNBR, kk = i - r*KNBR;
    int row = row0 + r;
    s_idx[i] = (row < NNODES) ? nbr[row*KNBR + kk] : 0;
  }
  __syncthreads();

  int lane = tid & 63;
  int wv = tid >> 6;
  int quad = lane >> 4, m = lane & 15;
  int qoff = quad * 8;
  int tt_w = wv >> 1, mat_w = wv & 1;         // this wave's staging slab
  const u16* wsrc = mat_w ? wb1h : wb1g;
  const int* idx = &s_idx[(wv*16 + m)*KNBR];

  f32x4 acc[2][4];
  f32x4 zz = {0.f,0.f,0.f,0.f};
  #pragma unroll
  for (int mt2=0;mt2<2;mt2++)
    #pragma unroll
    for (int i=0;i<4;i++) acc[mt2][i] = zz;

  bf16x8 as[3][2];

  // stage weight slices for k-step s into ws[s&1] (4 ops/wave = 4KB)
  #define STAGE_W1(s) { \
    u16* dst_ = ws + ((s)&1)*WSU + (tt_w*2+mat_w)*2048; \
    const u16* src_ = wsrc + ((size_t)(2*(s)+tt_w))*2048 + (size_t)lane*8; \
    _Pragma("unroll") \
    for (int ct_=0; ct_<4; ct_++) gl_lds16(src_ + ct_*512, dst_ + ct_*512); }

  #define LOAD_A1(s, d0, d1) { \
    const u16* r_ = sb + (size_t)idx[s]*64 + qoff; \
    d0 = *reinterpret_cast<const bf16x8*>(r_); \
    d1 = *reinterpret_cast<const bf16x8*>(r_ + 32); }

  // prologue queue: S0(4), A0(2), A1(2), A2(2)
  STAGE_W1(0); __builtin_amdgcn_sched_barrier(0);
  LOAD_A1(0, as[0][0], as[0][1]); __builtin_amdgcn_sched_barrier(0);
  LOAD_A1(1, as[1][0], as[1][1]); __builtin_amdgcn_sched_barrier(0);
  LOAD_A1(2, as[2][0], as[2][1]);

  #pragma unroll
  for (int k=0;k<KNBR;k++){
    // exact counted waits (see queue arithmetic in header comment):
    if (k == 0)       { WAITVM(4); }   // drain S0,A0; keep A1,A2
    else if (k <= 24) { WAITVM(2); }   // drain A(k+1)?,S(k); keep A(k+2)
    else              { WAITVM(0); }   // tail
    __builtin_amdgcn_s_barrier();      // publish S(k); buf[(k+1)&1] is free

    if (k+1 < KNBR) { STAGE_W1(k+1); }
    __builtin_amdgcn_sched_barrier(0); // keep stage-issue ahead of compute

    const u16* wsb = ws + (k&1)*WSU;
    #pragma unroll
    for (int tt=0;tt<2;tt++){
      bf16x8 af = as[k%3][tt];
      #pragma unroll
      for (int mt2=0;mt2<2;mt2++){
        #pragma unroll
        for (int ct=0;ct<4;ct++){
          bf16x8 b = *reinterpret_cast<const bf16x8*>(wsb + ((tt*2+mt2)*4+ct)*512 + (size_t)lane*8);
          acc[mt2][ct] = __builtin_amdgcn_mfma_f32_16x16x32_bf16(af, b, acc[mt2][ct], 0,0,0);
        }
      }
    }
    // A(k+3) into the slot MFMA just consumed ((k+3)%3 == k%3)
    if (k+3 < KNBR) { LOAD_A1(k+3, as[k%3][0], as[k%3][1]); }
  }
  __syncthreads();   // all waves done reading ws before sa alias-write

  // epilogue: wave-private LDS transpose
  #pragma unroll
  for (int mt2=0;mt2<2;mt2++){
    #pragma unroll
    for (int ct=0;ct<4;ct++){
      #pragma unroll
      for (int i=0;i<4;i++){
        int rl = wv*16 + quad*4 + i;
        sa[mt2*MR*APAD + rl*APAD + ct*16 + m] = f2bf(lrelu(acc[mt2][ct][i]));
      }
    }
  }
  // wave-private tile: no cross-wave barrier needed
  f32x4 d[2][4];
  #pragma unroll
  for (int mt2=0;mt2<2;mt2++)
    #pragma unroll
    for (int i=0;i<4;i++) d[mt2][i] = zz;
  #pragma unroll
  for (int c=0;c<2;c++){
    #pragma unroll
    for (int mt2=0;mt2<2;mt2++){
      bf16x8 a = *reinterpret_cast<const bf16x8*>(&sa[mt2*MR*APAD + (wv*16 + m)*APAD + c*32 + qoff]);
      #pragma unroll
      for (int ct=0;ct<4;ct++){
        const u16* wp = (mt2 ? wb2h : wb2g) + (((size_t)c*4+ct)*64 + lane)*8;
        bf16x8 b = *reinterpret_cast<const bf16x8*>(wp);
        d[mt2][ct] = __builtin_amdgcn_mfma_f32_16x16x32_bf16(a, b, d[mt2][ct], 0,0,0);
      }
    }
  }
  #pragma unroll
  for (int mt2=0;mt2<2;mt2++){
    #pragma unroll
    for (int ct=0;ct<4;ct++){
      #pragma unroll
      for (int i=0;i<4;i++){
        int row = row0 + wv*16 + quad*4 + i;
        if (row < NNODES){
          u[(size_t)row*128 + mt2*64 + ct*16 + m] = f2bf(lrelu(d[mt2][ct][i]));
        }
      }
    }
  }
  #undef STAGE_W1
  #undef LOAD_A1
}

// bg = gather(u[:,:64]) @ w3g ; bh = gather(u[:,64:]) @ w3h ;
// y = x_prev * exp(2*sigmoid(bg)-1) + bh -> out fp32; optionally y -> yb bf16.
// 4 waves x 16 rows, both matrices per wave (coupling in-register).
// Single barrier/iter, exact counted vmcnt.
__global__ __launch_bounds__(256,4) void conv2_coupling(
    const u16* __restrict__ ub,
    const int* __restrict__ nbr,
    const u16* __restrict__ wbg, const u16* __restrict__ wbh,
    const float* __restrict__ x, int xcol0,
    float* __restrict__ out, int ycol0,
    u16* __restrict__ yb, int write_yb)
{
  extern __shared__ char smem[];
  u16* ws    = (u16*)smem;                    // [2][WSU] = 32768 B
  int* s_idx = (int*)(smem + 2*WSU*2);        // [MR*KNBR] = 6912 B

  int tid = threadIdx.x;
  int row0 = blockIdx.x * MR;
  for (int i = tid; i < MR*KNBR; i += 256){
    int r = i / KNBR, kk = i - r*KNBR;
    int row = row0 + r;
    s_idx[i] = (row < NNODES) ? nbr[row*KNBR + kk] : 0;
  }
  __syncthreads();

  int lane = tid & 63;
  int wv = tid >> 6;
  int quad = lane >> 4, m = lane & 15;
  int qoff = quad * 8;
  int tt_w = wv >> 1, mat_w = wv & 1;
  const u16* wsrc = mat_w ? wbh : wbg;
  const int* idx = &s_idx[(wv*16 + m)*KNBR];

  f32x4 accg[4], acch[4];
  f32x4 zz = {0.f,0.f,0.f,0.f};
  #pragma unroll
  for (int i=0;i<4;i++){ accg[i]=zz; acch[i]=zz; }

  bf16x8 as[2][4];

  #define STAGE_W2(s) { \
    u16* dst_ = ws + ((s)&1)*WSU + (tt_w*2+mat_w)*2048; \
    const u16* src_ = wsrc + ((size_t)(2*(s)+tt_w))*2048 + (size_t)lane*8; \
    _Pragma("unroll") \
    for (int ct_=0; ct_<4; ct_++) gl_lds16(src_ + ct_*512, dst_ + ct_*512); }

  #define LOAD_A2(s, d0, d1, d2, d3) { \
    const u16* r_ = ub + (size_t)idx[s]*128 + qoff; \
    d0 = *reinterpret_cast<const bf16x8*>(r_); \
    d1 = *reinterpret_cast<const bf16x8*>(r_ + 32); \
    d2 = *reinterpret_cast<const bf16x8*>(r_ + 64); \
    d3 = *reinterpret_cast<const bf16x8*>(r_ + 96); }

  // prologue queue: S0(4), A0(4), A1(4)
  STAGE_W2(0); __builtin_amdgcn_sched_barrier(0);
  LOAD_A2(0, as[0][0], as[0][1], as[0][2], as[0][3]); __builtin_amdgcn_sched_barrier(0);
  LOAD_A2(1, as[1][0], as[1][1], as[1][2], as[1][3]);

  #pragma unroll
  for (int k=0;k<KNBR;k++){
    // steady queue at wait: A(k+1)4, S(k+1)?.. -> drain A(k)/S(k), keep newest 4
    if (k <= 25) { WAITVM(4); }
    else         { WAITVM(0); }
    __builtin_amdgcn_s_barrier();

    if (k+1 < KNBR) { STAGE_W2(k+1); }
    __builtin_amdgcn_sched_barrier(0);

    const u16* wsb = ws + (k&1)*WSU;
    #pragma unroll
    for (int tt=0;tt<2;tt++){
      bf16x8 ag = as[k&1][tt];       // g cols, k-half tt
      bf16x8 ah = as[k&1][2+tt];     // h cols
      #pragma unroll
      for (int ct=0;ct<4;ct++){
        bf16x8 bg = *reinterpret_cast<const bf16x8*>(wsb + ((tt*2+0)*4+ct)*512 + (size_t)lane*8);
        accg[ct] = __builtin_amdgcn_mfma_f32_16x16x32_bf16(ag, bg, accg[ct], 0,0,0);
      }
      #pragma unroll
      for (int ct=0;ct<4;ct++){
        bf16x8 bh = *reinterpret_cast<const bf16x8*>(wsb + ((tt*2+1)*4+ct)*512 + (size_t)lane*8);
        acch[ct] = __builtin_amdgcn_mfma_f32_16x16x32_bf16(ah, bh, acch[ct], 0,0,0);
      }
    }
    // A(k+2) into the slot MFMA just consumed ((k+2)&1 == k&1)
    if (k+2 < KNBR) { LOAD_A2(k+2, as[k&1][0], as[k&1][1], as[k&1][2], as[k&1][3]); }
  }

  // coupling epilogue: bg and bh live in the same wave — no LDS exchange
  #pragma unroll
  for (int ct=0;ct<4;ct++){
    #pragma unroll
    for (int i=0;i<4;i++){
      int row = row0 + wv*16 + quad*4 + i;
      if (row < NNODES){
        int col = ct*16 + m;
        float bg = accg[ct][i];
        float bh = acch[ct][i];
        float s = 1.f/(1.f + __expf(-bg));
        s = __expf(2.f*s - 1.f);
        float xv = x[(size_t)row*LDX + xcol0 + col];
        float y = xv*s + bh;
        out[(size_t)row*LDX + ycol0 + col] = y;
        if (write_yb) yb[(size_t)row*64 + col] = f2bf(y);
      }
    }
  }
  #undef STAGE_W2
  #undef LOAD_A2
}

extern "C" void kernel_launch(void* const* d_in, const int* in_sizes, int n_in,
                              void* d_out, int out_size, void* d_ws, size_t ws_size,
                              hipStream_t stream)
{
  const float* x   = (const float*)d_in[0];
  const int*   nbr = (const int*)d_in[1];
  const float* g1_w1=(const float*)d_in[2],  *g1_w2=(const float*)d_in[3],  *g1_w3=(const float*)d_in[4];
  const float* g2_w1=(const float*)d_in[5],  *g2_w2=(const float*)d_in[6],  *g2_w3=(const float*)d_in[7];
  const float* h1_w1=(const float*)d_in[8],  *h1_w2=(const float*)d_in[9],  *h1_w3=(const float*)d_in[10];
  const float* h2_w1=(const float*)d_in[11], *h2_w2=(const float*)d_in[12], *h2_w3=(const float*)d_in[13];
  float* out = (float*)d_out;
  u16* ws = (u16*)d_ws;

  const size_t WBB = (size_t)54*4*64*8;  // 1728-row weights (bf16 frags)
  const size_t WBS = (size_t)2*4*64*8;   // 64-row weights
  u16* p = ws;
  u16* wb_g2_1=p; p+=WBB;  u16* wb_h2_1=p; p+=WBB;
  u16* wb_g2_2=p; p+=WBS;  u16* wb_h2_2=p; p+=WBS;
  u16* wb_g2_3=p; p+=WBB;  u16* wb_h2_3=p; p+=WBB;
  u16* wb_g1_1=p; p+=WBB;  u16* wb_h1_1=p; p+=WBB;
  u16* wb_g1_2=p; p+=WBS;  u16* wb_h1_2=p; p+=WBS;
  u16* wb_g1_3=p; p+=WBB;  u16* wb_h1_3=p; p+=WBB;
  u16* ub = p; p += (size_t)NNODES*128;   // interleaved [g|h] bf16
  u16* sb = p; p += (size_t)NNODES*64;    // gather source (x2 bf16, then y1 bf16)

  reformat_w<<<54,256,0,stream>>>(g2_w1, wb_g2_1, 54);
  reformat_w<<<54,256,0,stream>>>(h2_w1, wb_h2_1, 54);
  reformat_w<<<2,256,0,stream>>>(g2_w2, wb_g2_2, 2);
  reformat_w<<<2,256,0,stream>>>(h2_w2, wb_h2_2, 2);
  reformat_w<<<54,256,0,stream>>>(g2_w3, wb_g2_3, 54);
  reformat_w<<<54,256,0,stream>>>(h2_w3, wb_h2_3, 54);
  reformat_w<<<54,256,0,stream>>>(g1_w1, wb_g1_1, 54);
  reformat_w<<<54,256,0,stream>>>(h1_w1, wb_h1_1, 54);
  reformat_w<<<2,256,0,stream>>>(g1_w2, wb_g1_2, 2);
  reformat_w<<<2,256,0,stream>>>(h1_w2, wb_h1_2, 2);
  reformat_w<<<54,256,0,stream>>>(g1_w3, wb_g1_3, 54);
  reformat_w<<<54,256,0,stream>>>(h1_w3, wb_h1_3, 54);

  conv_x2<<<(NNODES*64/8 + 255)/256, 256, 0, stream>>>(x, sb);

  int nblk = (NNODES + MR - 1)/MR;        // 2344
  size_t lds_sz = (size_t)2*WSU*2 + (size_t)MR*KNBR*4;  // 32768 + 6912 = 39680 B

  // Phase A: sb = x2(bf16); y1 -> out cols 0..63 + sb(bf16)
  conv1_fused<<<nblk,256,lds_sz,stream>>>(sb, nbr, wb_g2_1, wb_h2_1, wb_g2_2, wb_h2_2, ub);
  conv2_coupling<<<nblk,256,lds_sz,stream>>>(ub, nbr, wb_g2_3, wb_h2_3, x, 0, out, 0, sb, 1);
  // Phase B: sb = y1(bf16); y2 -> out cols 64..127
  conv1_fused<<<nblk,256,lds_sz,stream>>>(sb, nbr, wb_g1_1, wb_h1_1, wb_g1_2, wb_h1_2, ub);
  conv2_coupling<<<nblk,256,lds_sz,stream>>>(ub, nbr, wb_g1_3, wb_h1_3, x, 64, out, 64, sb, 0);
}

// Round 5
// 745.623 us; speedup vs baseline: 1.4744x; 1.0588x over previous
//
#include <hip/hip_runtime.h>
#include <stdint.h>

typedef unsigned short u16;
typedef __bf16 bf16x8 __attribute__((ext_vector_type(8)));
typedef float f32x4 __attribute__((ext_vector_type(4)));

#define NNODES 150000
#define KNBR 27
#define LDX 128
#define MR 128     // rows per block; 8 waves x 16 rows, each wave computes g AND h
#define APAD 72    // epilogue LDS row stride (u16)
#define WSU 8192   // u16 per 16KB weight stage buffer

#define WAITVM(N) asm volatile("s_waitcnt vmcnt(" #N ")" ::: "memory")

static __device__ __forceinline__ void gl_lds16(const u16* g, u16* l){
  __builtin_amdgcn_global_load_lds((const __attribute__((address_space(1))) void*)g,
                                   (__attribute__((address_space(3))) void*)l, 16, 0, 0);
}

static __device__ __forceinline__ u16 f2bf(float f){
  union { float f; uint32_t i; } v; v.f = f;
  uint32_t x = v.i;
  uint32_t r = (x + 0x7fffu + ((x >> 16) & 1u)) >> 16;  // RNE
  return (u16)r;
}
static __device__ __forceinline__ float lrelu(float v){ return v >= 0.f ? v : 0.2f*v; }

// fp32 weight (krows x 64) -> bf16 MFMA B-fragment order
__global__ void reformat_w(const float* __restrict__ src, u16* __restrict__ dst, int ksteps){
  int idx = blockIdx.x*256 + threadIdx.x;
  int total = ksteps*4*64;
  if (idx >= total) return;
  int lane = idx & 63;
  int ctile = (idx >> 6) & 3;
  int t = idx >> 8;
  int quad = lane >> 4, m = lane & 15;
  union { u16 h[8]; float4 v; } tmp;
  const float* s = src + ((size_t)(t*32 + quad*8))*64 + ctile*16 + m;
  #pragma unroll
  for (int j=0;j<8;j++) tmp.h[j] = f2bf(s[j*64]);
  *reinterpret_cast<float4*>(dst + (size_t)idx*8) = tmp.v;
}

// x cols 64..127 (fp32, LDX stride) -> bf16 table sb (N x 64)
__global__ void conv_x2(const float* __restrict__ x, u16* __restrict__ sb){
  int idx = blockIdx.x*256 + threadIdx.x;
  int e = idx*8;
  if (e >= NNODES*64) return;
  int row = e >> 6, col = e & 63;
  const float* s = x + (size_t)row*LDX + 64 + col;
  float4 a = *reinterpret_cast<const float4*>(s);
  float4 b = *reinterpret_cast<const float4*>(s+4);
  union { u16 h[8]; float4 v; } t;
  t.h[0]=f2bf(a.x); t.h[1]=f2bf(a.y); t.h[2]=f2bf(a.z); t.h[3]=f2bf(a.w);
  t.h[4]=f2bf(b.x); t.h[5]=f2bf(b.y); t.h[6]=f2bf(b.z); t.h[7]=f2bf(b.w);
  *reinterpret_cast<float4*>(sb + e) = t.v;
}

// Stage 2 of 16 weight chunks (1KB each) for k-step s into ws[s&1].
// chunk c = (tt*2+mat)*4+ct ; wave wv owns chunks 2wv, 2wv+1.
#define STAGE_W(s, wG, wH) { \
  u16* db_ = ws + ((s)&1)*WSU; \
  _Pragma("unroll") \
  for (int j_=0;j_<2;j_++){ \
    int c_ = wv*2 + j_; \
    int mat_ = (c_>>2)&1; int tt_ = c_>>3; int ct_ = c_&3; \
    const u16* src_ = (mat_ ? (wH) : (wG)) + ((size_t)(2*(s)+tt_))*2048 + (size_t)ct_*512 + (size_t)lane*8; \
    gl_lds16(src_, db_ + (size_t)c_*512); \
  } }

// u[:,0:64] = lrelu(lrelu(gather(sb) @ w1g) @ w2g); u[:,64:128] = h-version.
// 8 waves x 16 rows; each wave computes BOTH matrices.
// Weights LDS-staged (2 instr/wave/iter), single barrier/iter, counted vmcnt.
// w2 epilogue weights LDS-staged once per block.
__global__ __launch_bounds__(512,4) void conv1_fused(
    const u16* __restrict__ sb,
    const int* __restrict__ nbr,
    const u16* __restrict__ wb1g, const u16* __restrict__ wb1h,
    const u16* __restrict__ wb2g, const u16* __restrict__ wb2h,
    u16* __restrict__ u)
{
  extern __shared__ char smem[];
  u16* ws    = (u16*)smem;                    // [2][WSU] weight stages = 32768 B
  int* s_idx = (int*)(smem + 2*WSU*2);        // [MR*KNBR] = 13824 B (dies after k-loop)
  u16* sa    = (u16*)smem;                    // epilogue alias [2][MR*APAD] = 36864 B
  u16* w2l   = (u16*)(smem + 36864);          // epilogue w2 stage = 16384 B (tot 53248)

  int tid = threadIdx.x;
  int row0 = blockIdx.x * MR;
  for (int i = tid; i < MR*KNBR; i += 512){
    int r = i / KNBR, kk = i - r*KNBR;
    int row = row0 + r;
    s_idx[i] = (row < NNODES) ? nbr[row*KNBR + kk] : 0;
  }
  __syncthreads();

  int lane = tid & 63;
  int wv = tid >> 6;                          // 0..7
  int quad = lane >> 4, m = lane & 15;
  int qoff = quad * 8;
  const int* idx = &s_idx[(wv*16 + m)*KNBR];

  f32x4 acc[2][4];
  f32x4 zz = {0.f,0.f,0.f,0.f};
  #pragma unroll
  for (int mt2=0;mt2<2;mt2++)
    #pragma unroll
    for (int i=0;i<4;i++) acc[mt2][i] = zz;

  bf16x8 as[3][2];

  #define LOAD_A1(s, d0, d1) { \
    const u16* r_ = sb + (size_t)idx[s]*64 + qoff; \
    d0 = *reinterpret_cast<const bf16x8*>(r_); \
    d1 = *reinterpret_cast<const bf16x8*>(r_ + 32); }

  // prologue queue: S0(2), A0(2), A1(2), A2(2)
  STAGE_W(0, wb1g, wb1h); __builtin_amdgcn_sched_barrier(0);
  LOAD_A1(0, as[0][0], as[0][1]); __builtin_amdgcn_sched_barrier(0);
  LOAD_A1(1, as[1][0], as[1][1]); __builtin_amdgcn_sched_barrier(0);
  LOAD_A1(2, as[2][0], as[2][1]);

  #pragma unroll
  for (int k=0;k<KNBR;k++){
    // queue entering iter k (steady): [A(k+1)2, S(k)2, A(k+2)2]
    if (k == 0)       { WAITVM(4); }   // drain S0,A0; keep A1,A2
    else if (k <= 24) { WAITVM(2); }   // drain A(k+1),S(k); keep A(k+2)
    else              { WAITVM(0); }   // tail
    __builtin_amdgcn_s_barrier();      // publish S(k); buf[(k+1)&1] is free

    if (k+1 < KNBR) { STAGE_W(k+1, wb1g, wb1h); }
    __builtin_amdgcn_sched_barrier(0); // keep stage-issue ahead of compute

    const u16* wsb = ws + (k&1)*WSU;
    #pragma unroll
    for (int tt=0;tt<2;tt++){
      bf16x8 af = as[k%3][tt];
      #pragma unroll
      for (int mt2=0;mt2<2;mt2++){
        #pragma unroll
        for (int ct=0;ct<4;ct++){
          bf16x8 b = *reinterpret_cast<const bf16x8*>(wsb + ((tt*2+mt2)*4+ct)*512 + (size_t)lane*8);
          acc[mt2][ct] = __builtin_amdgcn_mfma_f32_16x16x32_bf16(af, b, acc[mt2][ct], 0,0,0);
        }
      }
    }
    // A(k+3) into the slot MFMA just consumed ((k+3)%3 == k%3)
    if (k+3 < KNBR) { LOAD_A1(k+3, as[k%3][0], as[k%3][1]); }
  }
  __syncthreads();   // all waves done with ws reads and s_idx

  // stage w2g+w2h (16KB, 16 chunks) into w2l: wave wv stages chunks 2wv,2wv+1
  #pragma unroll
  for (int j_=0;j_<2;j_++){
    int cc = wv*2 + j_;
    int mt2_ = cc>>3;                       // 0=g, 1=h
    const u16* src_ = (mt2_ ? wb2h : wb2g) + (size_t)(cc&7)*512 + (size_t)lane*8;
    gl_lds16(src_, w2l + (size_t)cc*512);
  }

  // lrelu -> bf16 tile in LDS (C-layout -> A-layout round trip); wave-private rows
  #pragma unroll
  for (int mt2=0;mt2<2;mt2++){
    #pragma unroll
    for (int ct=0;ct<4;ct++){
      #pragma unroll
      for (int i=0;i<4;i++){
        int rl = wv*16 + quad*4 + i;
        sa[mt2*MR*APAD + rl*APAD + ct*16 + m] = f2bf(lrelu(acc[mt2][ct][i]));
      }
    }
  }
  WAITVM(0);
  __syncthreads();   // w2l staged + sa visible

  f32x4 d[2][4];
  #pragma unroll
  for (int mt2=0;mt2<2;mt2++)
    #pragma unroll
    for (int i=0;i<4;i++) d[mt2][i] = zz;
  #pragma unroll
  for (int c=0;c<2;c++){
    #pragma unroll
    for (int mt2=0;mt2<2;mt2++){
      bf16x8 a = *reinterpret_cast<const bf16x8*>(&sa[mt2*MR*APAD + (wv*16 + m)*APAD + c*32 + qoff]);
      #pragma unroll
      for (int ct=0;ct<4;ct++){
        bf16x8 b = *reinterpret_cast<const bf16x8*>(w2l + (size_t)(mt2*8 + c*4 + ct)*512 + (size_t)lane*8);
        d[mt2][ct] = __builtin_amdgcn_mfma_f32_16x16x32_bf16(a, b, d[mt2][ct], 0,0,0);
      }
    }
  }
  #pragma unroll
  for (int mt2=0;mt2<2;mt2++){
    #pragma unroll
    for (int ct=0;ct<4;ct++){
      #pragma unroll
      for (int i=0;i<4;i++){
        int row = row0 + wv*16 + quad*4 + i;
        if (row < NNODES){
          u[(size_t)row*128 + mt2*64 + ct*16 + m] = f2bf(lrelu(d[mt2][ct][i]));
        }
      }
    }
  }
  #undef LOAD_A1
}

// bg = gather(u[:,:64]) @ w3g ; bh = gather(u[:,64:]) @ w3h ;
// y = x_prev * exp(2*sigmoid(bg)-1) + bh -> out fp32; optionally y -> yb bf16.
// 8 waves x 16 rows, both matrices per wave (coupling in-register).
__global__ __launch_bounds__(512,4) void conv2_coupling(
    const u16* __restrict__ ub,
    const int* __restrict__ nbr,
    const u16* __restrict__ wbg, const u16* __restrict__ wbh,
    const float* __restrict__ x, int xcol0,
    float* __restrict__ out, int ycol0,
    u16* __restrict__ yb, int write_yb)
{
  extern __shared__ char smem[];
  u16* ws    = (u16*)smem;                    // [2][WSU] = 32768 B
  int* s_idx = (int*)(smem + 2*WSU*2);        // [MR*KNBR] = 13824 B

  int tid = threadIdx.x;
  int row0 = blockIdx.x * MR;
  for (int i = tid; i < MR*KNBR; i += 512){
    int r = i / KNBR, kk = i - r*KNBR;
    int row = row0 + r;
    s_idx[i] = (row < NNODES) ? nbr[row*KNBR + kk] : 0;
  }
  __syncthreads();

  int lane = tid & 63;
  int wv = tid >> 6;                          // 0..7
  int quad = lane >> 4, m = lane & 15;
  int qoff = quad * 8;
  const int* idx = &s_idx[(wv*16 + m)*KNBR];

  f32x4 accg[4], acch[4];
  f32x4 zz = {0.f,0.f,0.f,0.f};
  #pragma unroll
  for (int i=0;i<4;i++){ accg[i]=zz; acch[i]=zz; }

  bf16x8 as[2][4];

  #define LOAD_A2(s, d0, d1, d2, d3) { \
    const u16* r_ = ub + (size_t)idx[s]*128 + qoff; \
    d0 = *reinterpret_cast<const bf16x8*>(r_); \
    d1 = *reinterpret_cast<const bf16x8*>(r_ + 32); \
    d2 = *reinterpret_cast<const bf16x8*>(r_ + 64); \
    d3 = *reinterpret_cast<const bf16x8*>(r_ + 96); }

  // prologue queue: S0(2), A0(4), A1(4)
  STAGE_W(0, wbg, wbh); __builtin_amdgcn_sched_barrier(0);
  LOAD_A2(0, as[0][0], as[0][1], as[0][2], as[0][3]); __builtin_amdgcn_sched_barrier(0);
  LOAD_A2(1, as[1][0], as[1][1], as[1][2], as[1][3]);

  #pragma unroll
  for (int k=0;k<KNBR;k++){
    // queue entering iter k (steady): [A(k)4, S(k)2, A(k+1)4]
    if (k < 26) { WAITVM(4); }   // drain A(k),S(k); keep A(k+1)
    else        { WAITVM(0); }
    __builtin_amdgcn_s_barrier();

    if (k+1 < KNBR) { STAGE_W(k+1, wbg, wbh); }
    __builtin_amdgcn_sched_barrier(0);

    const u16* wsb = ws + (k&1)*WSU;
    #pragma unroll
    for (int tt=0;tt<2;tt++){
      bf16x8 ag = as[k&1][tt];       // g cols, k-half tt
      bf16x8 ah = as[k&1][2+tt];     // h cols
      #pragma unroll
      for (int ct=0;ct<4;ct++){
        bf16x8 bg = *reinterpret_cast<const bf16x8*>(wsb + ((tt*2+0)*4+ct)*512 + (size_t)lane*8);
        accg[ct] = __builtin_amdgcn_mfma_f32_16x16x32_bf16(ag, bg, accg[ct], 0,0,0);
      }
      #pragma unroll
      for (int ct=0;ct<4;ct++){
        bf16x8 bh = *reinterpret_cast<const bf16x8*>(wsb + ((tt*2+1)*4+ct)*512 + (size_t)lane*8);
        acch[ct] = __builtin_amdgcn_mfma_f32_16x16x32_bf16(ah, bh, acch[ct], 0,0,0);
      }
    }
    // A(k+2) into the slot MFMA just consumed ((k+2)&1 == k&1)
    if (k+2 < KNBR) { LOAD_A2(k+2, as[k&1][0], as[k&1][1], as[k&1][2], as[k&1][3]); }
  }

  // coupling epilogue: bg and bh live in the same wave — no LDS exchange
  #pragma unroll
  for (int ct=0;ct<4;ct++){
    #pragma unroll
    for (int i=0;i<4;i++){
      int row = row0 + wv*16 + quad*4 + i;
      if (row < NNODES){
        int col = ct*16 + m;
        float bg = accg[ct][i];
        float bh = acch[ct][i];
        float s = 1.f/(1.f + __expf(-bg));
        s = __expf(2.f*s - 1.f);
        float xv = x[(size_t)row*LDX + xcol0 + col];
        float y = xv*s + bh;
        out[(size_t)row*LDX + ycol0 + col] = y;
        if (write_yb) yb[(size_t)row*64 + col] = f2bf(y);
      }
    }
  }
  #undef LOAD_A2
}

extern "C" void kernel_launch(void* const* d_in, const int* in_sizes, int n_in,
                              void* d_out, int out_size, void* d_ws, size_t ws_size,
                              hipStream_t stream)
{
  const float* x   = (const float*)d_in[0];
  const int*   nbr = (const int*)d_in[1];
  const float* g1_w1=(const float*)d_in[2],  *g1_w2=(const float*)d_in[3],  *g1_w3=(const float*)d_in[4];
  const float* g2_w1=(const float*)d_in[5],  *g2_w2=(const float*)d_in[6],  *g2_w3=(const float*)d_in[7];
  const float* h1_w1=(const float*)d_in[8],  *h1_w2=(const float*)d_in[9],  *h1_w3=(const float*)d_in[10];
  const float* h2_w1=(const float*)d_in[11], *h2_w2=(const float*)d_in[12], *h2_w3=(const float*)d_in[13];
  float* out = (float*)d_out;
  u16* ws = (u16*)d_ws;

  const size_t WBB = (size_t)54*4*64*8;  // 1728-row weights (bf16 frags)
  const size_t WBS = (size_t)2*4*64*8;   // 64-row weights
  u16* p = ws;
  u16* wb_g2_1=p; p+=WBB;  u16* wb_h2_1=p; p+=WBB;
  u16* wb_g2_2=p; p+=WBS;  u16* wb_h2_2=p; p+=WBS;
  u16* wb_g2_3=p; p+=WBB;  u16* wb_h2_3=p; p+=WBB;
  u16* wb_g1_1=p; p+=WBB;  u16* wb_h1_1=p; p+=WBB;
  u16* wb_g1_2=p; p+=WBS;  u16* wb_h1_2=p; p+=WBS;
  u16* wb_g1_3=p; p+=WBB;  u16* wb_h1_3=p; p+=WBB;
  u16* ub = p; p += (size_t)NNODES*128;   // interleaved [g|h] bf16
  u16* sb = p; p += (size_t)NNODES*64;    // gather source (x2 bf16, then y1 bf16)

  reformat_w<<<54,256,0,stream>>>(g2_w1, wb_g2_1, 54);
  reformat_w<<<54,256,0,stream>>>(h2_w1, wb_h2_1, 54);
  reformat_w<<<2,256,0,stream>>>(g2_w2, wb_g2_2, 2);
  reformat_w<<<2,256,0,stream>>>(h2_w2, wb_h2_2, 2);
  reformat_w<<<54,256,0,stream>>>(g2_w3, wb_g2_3, 54);
  reformat_w<<<54,256,0,stream>>>(h2_w3, wb_h2_3, 54);
  reformat_w<<<54,256,0,stream>>>(g1_w1, wb_g1_1, 54);
  reformat_w<<<54,256,0,stream>>>(h1_w1, wb_h1_1, 54);
  reformat_w<<<2,256,0,stream>>>(g1_w2, wb_g1_2, 2);
  reformat_w<<<2,256,0,stream>>>(h1_w2, wb_h1_2, 2);
  reformat_w<<<54,256,0,stream>>>(g1_w3, wb_g1_3, 54);
  reformat_w<<<54,256,0,stream>>>(h1_w3, wb_h1_3, 54);

  conv_x2<<<(NNODES*64/8 + 255)/256, 256, 0, stream>>>(x, sb);

  int nblk = (NNODES + MR - 1)/MR;        // 1172
  size_t c1_lds = 53248;                  // ws 32K + s_idx 13.8K; epi: sa 36K + w2l 16K
  size_t c2_lds = (size_t)2*WSU*2 + (size_t)MR*KNBR*4;  // 46592 B

  // Phase A: sb = x2(bf16); y1 -> out cols 0..63 + sb(bf16)
  conv1_fused<<<nblk,512,c1_lds,stream>>>(sb, nbr, wb_g2_1, wb_h2_1, wb_g2_2, wb_h2_2, ub);
  conv2_coupling<<<nblk,512,c2_lds,stream>>>(ub, nbr, wb_g2_3, wb_h2_3, x, 0, out, 0, sb, 1);
  // Phase B: sb = y1(bf16); y2 -> out cols 64..127
  conv1_fused<<<nblk,512,c1_lds,stream>>>(sb, nbr, wb_g1_1, wb_h1_1, wb_g1_2, wb_h1_2, ub);
  conv2_coupling<<<nblk,512,c2_lds,stream>>>(ub, nbr, wb_g1_3, wb_h1_3, x, 64, out, 64, sb, 0);
}